// Round 1
// baseline (30711.346 us; speedup 1.0000x reference)
//
#include <hip/hip_runtime.h>
#include <hip/hip_bf16.h>

// ---------------- problem constants ----------------
#define PB 64      // batch
#define PN 512     // set size
#define PFEA 102
#define PE 10
#define PDD 256    // d
#define PH 4
#define PDBIG 1024 // D = d*H
#define PL 3
#define PNDIST 100

// ---------------- helpers ----------------
__device__ __forceinline__ float block_sum256(float v, float* red, int tid) {
    red[tid] = v; __syncthreads();
    #pragma unroll
    for (int s = 128; s > 0; s >>= 1) {
        if (tid < s) red[tid] += red[tid + s];
        __syncthreads();
    }
    float r = red[0]; __syncthreads();
    return r;
}

__device__ __forceinline__ float block_max256(float v, float* red, int tid) {
    red[tid] = v; __syncthreads();
    #pragma unroll
    for (int s = 128; s > 0; s >>= 1) {
        if (tid < s) red[tid] = fmaxf(red[tid], red[tid + s]);
        __syncthreads();
    }
    float r = red[0]; __syncthreads();
    return r;
}

// ---------------- embed: comp + strf + LN -> x, x_init ----------------
__global__ __launch_bounds__(256) void pst_embed_kernel(
    const float* __restrict__ features, const float* __restrict__ atom_fea,
    const float* __restrict__ comp_W, const float* __restrict__ comp_b,
    const float* __restrict__ emb_W, const float* __restrict__ emb_b,
    const float* __restrict__ ln_g, const float* __restrict__ ln_b,
    float* __restrict__ x, float* __restrict__ x_init)
{
    int r = blockIdx.x;                  // 0 .. B*N-1
    int tid = threadIdx.x;               // 0..255, one output channel each
    __shared__ float afea[92];
    __shared__ float de[PNDIST * PE];    // 1000
    __shared__ float red[256];

    const float* frow = features + (long)r * PFEA;
    int idx = (int)frow[PFEA - 1];
    if (tid < 92) afea[tid] = atom_fea[idx * 92 + tid];
    for (int m = tid; m < PNDIST * PE; m += 256) {
        int f = m / PE, t = m % PE;
        float dv = frow[1 + f];
        float u = 1.0f - (dv - 0.1f * (float)t);
        de[m] = u * u;
    }
    __syncthreads();

    float acc = comp_b[tid] + emb_b[tid];
    #pragma unroll 4
    for (int c = 0; c < 92; ++c)
        acc = fmaf(afea[c], comp_W[c * PDD + tid], acc);
    #pragma unroll 4
    for (int m = 0; m < PNDIST * PE; ++m)
        acc = fmaf(de[m], emb_W[m * PDD + tid], acc);

    // LayerNorm over 256
    float mean = block_sum256(acc, red, tid) * (1.0f / PDD);
    float dv = acc - mean;
    float var = block_sum256(dv * dv, red, tid) * (1.0f / PDD);
    float y = dv * rsqrtf(var + 1e-5f) * ln_g[tid] + ln_b[tid];

    long o = (long)r * PDD + tid;
    x[o] = y;
    x_init[o] = y;
}

// ---------------- generic tiled fp32 GEMM: C = A(MxK) @ B(KxN) + bias ----------------
#define GT 64
#define GK 16
__global__ __launch_bounds__(256) void pst_gemm_f32(
    const float* __restrict__ A, const float* __restrict__ Bm,
    const float* __restrict__ bias, float* __restrict__ C,
    int M, int Nn, int K, int lda, int ldb, int ldc,
    long sA, long sB, long sC)
{
    int bz = blockIdx.z;
    A += bz * sA; Bm += bz * sB; C += bz * sC;
    __shared__ float As[GK][GT + 4];
    __shared__ float Bs[GK][GT + 4];
    int tid = threadIdx.x;
    int tx = tid & 15, ty = tid >> 4;
    int m0 = blockIdx.y * GT, n0 = blockIdx.x * GT;
    float acc[4][4] = {};
    for (int k0 = 0; k0 < K; k0 += GK) {
        {
            int m = tid >> 2, kk = (tid & 3) << 2;
            const float4 av = *(const float4*)(A + (long)(m0 + m) * lda + k0 + kk);
            As[kk + 0][m] = av.x; As[kk + 1][m] = av.y;
            As[kk + 2][m] = av.z; As[kk + 3][m] = av.w;
        }
        {
            int kk = tid >> 4, n = (tid & 15) << 2;
            const float4 bv = *(const float4*)(Bm + (long)(k0 + kk) * ldb + n0 + n);
            Bs[kk][n + 0] = bv.x; Bs[kk][n + 1] = bv.y;
            Bs[kk][n + 2] = bv.z; Bs[kk][n + 3] = bv.w;
        }
        __syncthreads();
        #pragma unroll
        for (int kk = 0; kk < GK; ++kk) {
            float a[4], b[4];
            #pragma unroll
            for (int i = 0; i < 4; ++i) a[i] = As[kk][ty * 4 + i];
            #pragma unroll
            for (int j = 0; j < 4; ++j) b[j] = Bs[kk][tx * 4 + j];
            #pragma unroll
            for (int i = 0; i < 4; ++i)
                #pragma unroll
                for (int j = 0; j < 4; ++j)
                    acc[i][j] = fmaf(a[i], b[j], acc[i][j]);
        }
        __syncthreads();
    }
    #pragma unroll
    for (int i = 0; i < 4; ++i) {
        int m = m0 + ty * 4 + i;
        #pragma unroll
        for (int j = 0; j < 4; ++j) {
            int n = n0 + tx * 4 + j;
            float v = acc[i][j] + (bias ? bias[n] : 0.0f);
            C[(long)m * ldc + n] = v;
        }
    }
}

// ---------------- mask: sum|e| == 0 ----------------
__global__ __launch_bounds__(256) void pst_mask_kernel(
    const float* __restrict__ e, float* __restrict__ mask)
{
    int r = blockIdx.x;
    int tid = threadIdx.x;
    __shared__ float red[256];
    float s = 0.0f;
    for (int i = tid; i < PDBIG; i += 256)
        s += fabsf(e[(long)r * PDBIG + i]);
    float tot = block_sum256(s, red, tid);
    if (tid == 0) mask[r] = (tot == 0.0f) ? 1.0f : 0.0f;
}

// ---------------- scores -> softmax -> mean heads -> *w -> renorm -> A ----------------
// one block = 4 q rows of one (local) batch
__global__ __launch_bounds__(256) void pst_attnA_kernel(
    const float* __restrict__ q, const float* __restrict__ k,
    const float* __restrict__ mask, const float* __restrict__ features,
    float* __restrict__ A, int bGlobBase)
{
    int blk = blockIdx.x;
    int bLoc = blk >> 7;             // 128 q-blocks per batch
    int q0 = (blk & 127) << 2;
    int tid = threadIdx.x;
    __shared__ float qs[4][PDBIG];
    __shared__ float sc[4][PN];
    __shared__ float pacc[4][PN];
    __shared__ float wm[PN];
    __shared__ float red[256];

    long qbase = ((long)(bLoc * PN + q0)) * PDBIG;
    for (int i = tid; i < 4 * PDBIG; i += 256)
        qs[i >> 10][i & (PDBIG - 1)] = q[qbase + i];
    int bGlob = bGlobBase + bLoc;
    for (int c = tid; c < PN; c += 256) {
        wm[c] = features[(((long)bGlob * PN) + c) * PFEA];
        pacc[0][c] = 0.0f; pacc[1][c] = 0.0f; pacc[2][c] = 0.0f; pacc[3][c] = 0.0f;
    }
    __syncthreads();

    const float scale = 0.0625f;   // 1/sqrt(256)
    float mk0 = mask[bLoc * PN + tid];
    float mk1 = mask[bLoc * PN + tid + 256];

    for (int h = 0; h < PH; ++h) {
        #pragma unroll
        for (int cc = 0; cc < 2; ++cc) {
            int c = tid + cc * 256;
            const float* krow = k + ((long)(bLoc * PN + c)) * PDBIG + h * PDD;
            const float* q0p = &qs[0][h * PDD];
            const float* q1p = &qs[1][h * PDD];
            const float* q2p = &qs[2][h * PDD];
            const float* q3p = &qs[3][h * PDD];
            float s0 = 0, s1 = 0, s2 = 0, s3 = 0;
            #pragma unroll 4
            for (int i = 0; i < PDD; ++i) {
                float kv = krow[i];
                s0 = fmaf(q0p[i], kv, s0);
                s1 = fmaf(q1p[i], kv, s1);
                s2 = fmaf(q2p[i], kv, s2);
                s3 = fmaf(q3p[i], kv, s3);
            }
            float mk = (cc == 0) ? mk0 : mk1;
            bool bad = (mk != 0.0f);
            sc[0][c] = bad ? -1e9f : s0 * scale;
            sc[1][c] = bad ? -1e9f : s1 * scale;
            sc[2][c] = bad ? -1e9f : s2 * scale;
            sc[3][c] = bad ? -1e9f : s3 * scale;
        }
        __syncthreads();
        for (int j = 0; j < 4; ++j) {
            float v0 = sc[j][tid], v1 = sc[j][tid + 256];
            float mx = block_max256(fmaxf(v0, v1), red, tid);
            float e0 = expf(v0 - mx), e1 = expf(v1 - mx);
            float ssum = block_sum256(e0 + e1, red, tid);
            float inv = 1.0f / ssum;
            pacc[j][tid] += e0 * inv;
            pacc[j][tid + 256] += e1 * inv;
        }
        __syncthreads();
    }
    for (int j = 0; j < 4; ++j) {
        float a0 = pacc[j][tid] * wm[tid];
        float a1 = pacc[j][tid + 256] * wm[tid + 256];
        float rs = block_sum256(a0 + a1, red, tid);
        float inv = 1.0f / rs;
        long row = (long)(bLoc * PN + q0 + j) * PN;
        A[row + tid] = a0 * inv;
        A[row + tid + 256] = a1 * inv;
    }
}

// ---------------- xe = LN(e + softplus(att)) (in place over e) ----------------
__global__ __launch_bounds__(256) void pst_spln_kernel(
    const float* __restrict__ att, float* __restrict__ e,
    const float* __restrict__ g, const float* __restrict__ b)
{
    int r = blockIdx.x;
    int tid = threadIdx.x;
    __shared__ float red[256];
    float v[4];
    float s = 0.0f;
    #pragma unroll
    for (int j = 0; j < 4; ++j) {
        int i = tid + j * 256;
        float a = att[(long)r * PDBIG + i];
        float sp = (a > 20.0f) ? a : log1pf(expf(a));
        v[j] = e[(long)r * PDBIG + i] + sp;
        s += v[j];
    }
    float mean = block_sum256(s, red, tid) * (1.0f / PDBIG);
    float vs = 0.0f;
    #pragma unroll
    for (int j = 0; j < 4; ++j) { float dv = v[j] - mean; vs += dv * dv; }
    float var = block_sum256(vs, red, tid) * (1.0f / PDBIG);
    float inv = rsqrtf(var + 1e-5f);
    #pragma unroll
    for (int j = 0; j < 4; ++j) {
        int i = tid + j * 256;
        e[(long)r * PDBIG + i] = (v[j] - mean) * inv * g[i] + b[i];
    }
}

// ---------------- pooled = LN(sum_n w*(x+x_init)); out = pooled@out_W + b ----------------
__global__ __launch_bounds__(256) void pst_pool_kernel(
    const float* __restrict__ features, const float* __restrict__ x,
    const float* __restrict__ x_init, const float* __restrict__ ln_g,
    const float* __restrict__ ln_b, const float* __restrict__ out_W,
    const float* __restrict__ out_b, float* __restrict__ out)
{
    int b = blockIdx.x;
    int tid = threadIdx.x;
    __shared__ float red[256];
    float acc = 0.0f;
    for (int n = 0; n < PN; ++n) {
        float w = features[(((long)b * PN) + n) * PFEA];
        long off = (((long)b * PN) + n) * PDD + tid;
        acc = fmaf(w, x[off] + x_init[off], acc);
    }
    float mean = block_sum256(acc, red, tid) * (1.0f / PDD);
    float dv = acc - mean;
    float var = block_sum256(dv * dv, red, tid) * (1.0f / PDD);
    float y = dv * rsqrtf(var + 1e-5f) * ln_g[tid] + ln_b[tid];
    float s = block_sum256(y * out_W[tid], red, tid);
    if (tid == 0) out[b] = s + out_b[0];
}

// ---------------- host ----------------
static void launch_gemm(const float* A, const float* Bm, const float* bias, float* C,
                        int M, int Nn, int K, int lda, int ldb, int ldc,
                        long sA, long sB, long sC, int batch, hipStream_t stream)
{
    dim3 grid(Nn / GT, M / GT, batch);
    pst_gemm_f32<<<grid, dim3(256), 0, stream>>>(A, Bm, bias, C, M, Nn, K, lda, ldb, ldc, sA, sB, sC);
}

extern "C" void kernel_launch(void* const* d_in, const int* in_sizes, int n_in,
                              void* d_out, int out_size, void* d_ws, size_t ws_size,
                              hipStream_t stream)
{
    const float* features  = (const float*)d_in[0];
    const float* atom_fea  = (const float*)d_in[1];
    const float* comp_W    = (const float*)d_in[2];
    const float* comp_b    = (const float*)d_in[3];
    const float* emb_W     = (const float*)d_in[4];
    const float* emb_b     = (const float*)d_in[5];
    const float* ln_g      = (const float*)d_in[6];
    const float* ln_b      = (const float*)d_in[7];
    const float* enc_emb_W = (const float*)d_in[8];
    const float* enc_emb_b = (const float*)d_in[9];
    const float* enc_Wq_W  = (const float*)d_in[10];
    const float* enc_Wq_b  = (const float*)d_in[11];
    const float* enc_Wk_W  = (const float*)d_in[12];
    const float* enc_Wk_b  = (const float*)d_in[13];
    const float* enc_Wv_W  = (const float*)d_in[14];
    const float* enc_Wv_b  = (const float*)d_in[15];
    const float* enc_inq_W = (const float*)d_in[16];
    const float* enc_inq_b = (const float*)d_in[17];
    const float* enc_ink_W = (const float*)d_in[18];
    const float* enc_ink_b = (const float*)d_in[19];
    const float* enc_ln_g  = (const float*)d_in[20];
    const float* enc_ln_b  = (const float*)d_in[21];
    const float* enc_out_W = (const float*)d_in[22];
    const float* enc_out_b = (const float*)d_in[23];
    const float* out_W     = (const float*)d_in[24];
    const float* out_b     = (const float*)d_in[25];

    // pick batch chunk CB so workspace fits
    int CB = 16;
    size_t fixedf = (size_t)2 * PB * PN * PDD;  // x + x_init (floats)
    while (CB > 1) {
        size_t needf = fixedf + (size_t)CB * PN * (4 * PDBIG + PN + 1);
        if (needf * sizeof(float) <= ws_size) break;
        CB >>= 1;
    }

    float* ws = (float*)d_ws;
    size_t off = 0;
    float* x      = ws + off; off += (size_t)PB * PN * PDD;
    float* x_init = ws + off; off += (size_t)PB * PN * PDD;
    float* e      = ws + off; off += (size_t)CB * PN * PDBIG;
    float* t1     = ws + off; off += (size_t)CB * PN * PDBIG;   // qtmp/ktmp then v
    float* b1     = ws + off; off += (size_t)CB * PN * PDBIG;   // q then att
    float* b2     = ws + off; off += (size_t)CB * PN * PDBIG;   // k
    float* Abuf   = ws + off; off += (size_t)CB * PN * PN;
    float* maskb  = ws + off; off += (size_t)CB * PN;

    // embedding for all rows
    pst_embed_kernel<<<dim3(PB * PN), dim3(256), 0, stream>>>(
        features, atom_fea, comp_W, comp_b, emb_W, emb_b, ln_g, ln_b, x, x_init);

    for (int cb0 = 0; cb0 < PB; cb0 += CB) {
        float* xs = x + (size_t)cb0 * PN * PDD;
        int M = CB * PN;
        for (int l = 0; l < PL; ++l) {
            const float* Wemb = enc_emb_W + (size_t)l * PDD * PDBIG;
            launch_gemm(xs, Wemb, enc_emb_b + (size_t)l * PDBIG, e,
                        M, PDBIG, PDD, PDD, PDBIG, PDBIG, 0, 0, 0, 1, stream);
            // q = (e@Wq + bq) @ inq + binq
            launch_gemm(e, enc_Wq_W + (size_t)l * PDBIG * PDBIG, enc_Wq_b + (size_t)l * PDBIG, t1,
                        M, PDBIG, PDBIG, PDBIG, PDBIG, PDBIG, 0, 0, 0, 1, stream);
            launch_gemm(t1, enc_inq_W + (size_t)l * PDBIG * PDBIG, enc_inq_b + (size_t)l * PDBIG, b1,
                        M, PDBIG, PDBIG, PDBIG, PDBIG, PDBIG, 0, 0, 0, 1, stream);
            // k
            launch_gemm(e, enc_Wk_W + (size_t)l * PDBIG * PDBIG, enc_Wk_b + (size_t)l * PDBIG, t1,
                        M, PDBIG, PDBIG, PDBIG, PDBIG, PDBIG, 0, 0, 0, 1, stream);
            launch_gemm(t1, enc_ink_W + (size_t)l * PDBIG * PDBIG, enc_ink_b + (size_t)l * PDBIG, b2,
                        M, PDBIG, PDBIG, PDBIG, PDBIG, PDBIG, 0, 0, 0, 1, stream);
            // v (into t1)
            launch_gemm(e, enc_Wv_W + (size_t)l * PDBIG * PDBIG, enc_Wv_b + (size_t)l * PDBIG, t1,
                        M, PDBIG, PDBIG, PDBIG, PDBIG, PDBIG, 0, 0, 0, 1, stream);
            // mask from e
            pst_mask_kernel<<<dim3(M), dim3(256), 0, stream>>>(e, maskb);
            // A
            pst_attnA_kernel<<<dim3(CB * 128), dim3(256), 0, stream>>>(
                b1, b2, maskb, features, Abuf, cb0);
            // att = A @ v  (batched) -> b1
            launch_gemm(Abuf, t1, nullptr, b1, PN, PDBIG, PN, PN, PDBIG, PDBIG,
                        (long)PN * PN, (long)PN * PDBIG, (long)PN * PDBIG, CB, stream);
            // xe = LN(e + softplus(att)) in place over e
            pst_spln_kernel<<<dim3(M), dim3(256), 0, stream>>>(
                b1, e, enc_ln_g + (size_t)l * PDBIG, enc_ln_b + (size_t)l * PDBIG);
            // x = xe @ out_W + b
            launch_gemm(e, enc_out_W + (size_t)l * PDBIG * PDD, enc_out_b + (size_t)l * PDD, xs,
                        M, PDD, PDBIG, PDBIG, PDD, PDD, 0, 0, 0, 1, stream);
        }
    }

    pst_pool_kernel<<<dim3(PB), dim3(256), 0, stream>>>(
        features, x, x_init, ln_g, ln_b, out_W, out_b, (float*)d_out);
}

// Round 2
// 19462.823 us; speedup vs baseline: 1.5779x; 1.5779x over previous
//
#include <hip/hip_runtime.h>
#include <hip/hip_bf16.h>

// ---------------- problem constants ----------------
#define PB 64      // batch
#define PN 512     // set size
#define PFEA 102
#define PE 10
#define PDD 256    // d
#define PH 4
#define PDBIG 1024 // D = d*H
#define PL 3
#define PNDIST 100

typedef __attribute__((ext_vector_type(8))) short s8b;   // 8 bf16 (4 VGPRs)
typedef __attribute__((ext_vector_type(4))) float f4;    // 4 fp32 acc

typedef __attribute__((address_space(1))) const void gvoid_t;
typedef __attribute__((address_space(3))) void lvoid_t;
#define GLDS16(g, s) __builtin_amdgcn_global_load_lds((gvoid_t*)(g), (lvoid_t*)(s), 16, 0, 0)

__device__ __forceinline__ void split_bf16(float v, __hip_bfloat16& hi, __hip_bfloat16& lo) {
    hi = __float2bfloat16(v);
    lo = __float2bfloat16(v - __bfloat162float(hi));
}

// ---------------- helpers ----------------
__device__ __forceinline__ float block_sum256(float v, float* red, int tid) {
    red[tid] = v; __syncthreads();
    #pragma unroll
    for (int s = 128; s > 0; s >>= 1) {
        if (tid < s) red[tid] += red[tid + s];
        __syncthreads();
    }
    float r = red[0]; __syncthreads();
    return r;
}

__device__ __forceinline__ float block_max256(float v, float* red, int tid) {
    red[tid] = v; __syncthreads();
    #pragma unroll
    for (int s = 128; s > 0; s >>= 1) {
        if (tid < s) red[tid] = fmaxf(red[tid], red[tid + s]);
        __syncthreads();
    }
    float r = red[0]; __syncthreads();
    return r;
}

// ---------------- embed: comp + strf + LN -> x, x_init ----------------
__global__ __launch_bounds__(256) void pst_embed_kernel(
    const float* __restrict__ features, const float* __restrict__ atom_fea,
    const float* __restrict__ comp_W, const float* __restrict__ comp_b,
    const float* __restrict__ emb_W, const float* __restrict__ emb_b,
    const float* __restrict__ ln_g, const float* __restrict__ ln_b,
    float* __restrict__ x, float* __restrict__ x_init)
{
    int r = blockIdx.x;
    int tid = threadIdx.x;
    __shared__ float afea[92];
    __shared__ float de[PNDIST * PE];
    __shared__ float red[256];

    const float* frow = features + (long)r * PFEA;
    int idx = (int)frow[PFEA - 1];
    if (tid < 92) afea[tid] = atom_fea[idx * 92 + tid];
    for (int m = tid; m < PNDIST * PE; m += 256) {
        int f = m / PE, t = m % PE;
        float dv = frow[1 + f];
        float u = 1.0f - (dv - 0.1f * (float)t);
        de[m] = u * u;
    }
    __syncthreads();

    float acc = comp_b[tid] + emb_b[tid];
    #pragma unroll 4
    for (int c = 0; c < 92; ++c)
        acc = fmaf(afea[c], comp_W[c * PDD + tid], acc);
    #pragma unroll 4
    for (int m = 0; m < PNDIST * PE; ++m)
        acc = fmaf(de[m], emb_W[m * PDD + tid], acc);

    float mean = block_sum256(acc, red, tid) * (1.0f / PDD);
    float dv = acc - mean;
    float var = block_sum256(dv * dv, red, tid) * (1.0f / PDD);
    float y = dv * rsqrtf(var + 1e-5f) * ln_g[tid] + ln_b[tid];

    long o = (long)r * PDD + tid;
    x[o] = y;
    x_init[o] = y;
}

// ---------------- fp32 GEMM (used only for weight-combine Wq@inq) ----------------
#define GT 64
#define GK 16
__global__ __launch_bounds__(256) void pst_gemm_f32(
    const float* __restrict__ A, const float* __restrict__ Bm,
    const float* __restrict__ bias, float* __restrict__ C,
    int M, int Nn, int K, int lda, int ldb, int ldc)
{
    __shared__ float As[GK][GT + 4];
    __shared__ float Bs[GK][GT + 4];
    int tid = threadIdx.x;
    int tx = tid & 15, ty = tid >> 4;
    int m0 = blockIdx.y * GT, n0 = blockIdx.x * GT;
    float acc[4][4] = {};
    for (int k0 = 0; k0 < K; k0 += GK) {
        {
            int m = tid >> 2, kk = (tid & 3) << 2;
            const float4 av = *(const float4*)(A + (long)(m0 + m) * lda + k0 + kk);
            As[kk + 0][m] = av.x; As[kk + 1][m] = av.y;
            As[kk + 2][m] = av.z; As[kk + 3][m] = av.w;
        }
        {
            int kk = tid >> 4, n = (tid & 15) << 2;
            const float4 bv = *(const float4*)(Bm + (long)(k0 + kk) * ldb + n0 + n);
            Bs[kk][n + 0] = bv.x; Bs[kk][n + 1] = bv.y;
            Bs[kk][n + 2] = bv.z; Bs[kk][n + 3] = bv.w;
        }
        __syncthreads();
        #pragma unroll
        for (int kk = 0; kk < GK; ++kk) {
            float a[4], b[4];
            #pragma unroll
            for (int i = 0; i < 4; ++i) a[i] = As[kk][ty * 4 + i];
            #pragma unroll
            for (int j = 0; j < 4; ++j) b[j] = Bs[kk][tx * 4 + j];
            #pragma unroll
            for (int i = 0; i < 4; ++i)
                #pragma unroll
                for (int j = 0; j < 4; ++j)
                    acc[i][j] = fmaf(a[i], b[j], acc[i][j]);
        }
        __syncthreads();
    }
    #pragma unroll
    for (int i = 0; i < 4; ++i) {
        int m = m0 + ty * 4 + i;
        #pragma unroll
        for (int j = 0; j < 4; ++j) {
            int n = n0 + tx * 4 + j;
            float v = acc[i][j] + (bias ? bias[n] : 0.0f);
            C[(long)m * ldc + n] = v;
        }
    }
}

// ---------------- bf16 split-K MFMA GEMM ----------------
// A pack: M x 2K  [hi | lo], row-major (A-operand)
// B pack: N x 2K  [hi | lo], row-major = B^T layout (B-operand)
// effective compute: Ah@Bh + Al@Bh + Ah@Bl  (K-loop runs 3K with block remap)
// MODE 0: C f32 only. MODE 1: C f32 + P = row-pack of C (M x 2Nw).
// MODE 2: P only = per-batch transposed pack (vpT: [b][n][2*512]), no C.
template<int MODE>
__global__ __launch_bounds__(256) void pst_gemm_bf16(
    const __hip_bfloat16* __restrict__ Ap, const __hip_bfloat16* __restrict__ Bp,
    const float* __restrict__ bias, float* __restrict__ C,
    __hip_bfloat16* __restrict__ P,
    int K, int Nw, long strideA, long strideB, long strideC)
{
    const int lda = 2 * K, ldb = 2 * K;
    int bz = blockIdx.z;
    Ap += (long)bz * strideA; Bp += (long)bz * strideB;
    if (MODE != 2) C += (long)bz * strideC;

    __shared__ __hip_bfloat16 As[128 * 32];   // [128 m][32 k]
    __shared__ __hip_bfloat16 Bs[128 * 32];   // [128 n][32 k]

    int tid = threadIdx.x;
    int w = tid >> 6, l = tid & 63;
    int r4 = tid >> 2;               // 0..63 (row pairs for staging)
    int c8 = (tid & 3) * 8;          // k-offset for staging
    int m0 = blockIdx.y * 128, n0 = blockIdx.x * 128;
    int lr = l & 15, kb = l >> 4;    // fragment row/col + k-block
    int wm = (w >> 1) * 64, wn = (w & 1) * 64;

    f4 acc[4][4] = {};

    const int K3 = 3 * K;
    for (int k0 = 0; k0 < K3; k0 += 32) {
        int kA = (k0 < 2 * K) ? k0 : k0 - 2 * K;   // block order: hi, lo, hi
        int kB = (k0 < K) ? k0 : k0 - K;           // block order: hi, hi, lo
        const __hip_bfloat16* ga = Ap + (long)(m0 + r4) * lda + kA + c8;
        const __hip_bfloat16* gb = Bp + (long)(n0 + r4) * ldb + kB + c8;
        GLDS16(ga,             As + w * 512);
        GLDS16(ga + 64L * lda, As + 2048 + w * 512);
        GLDS16(gb,             Bs + w * 512);
        GLDS16(gb + 64L * ldb, Bs + 2048 + w * 512);
        __syncthreads();

        s8b af[4], bf[4];
        #pragma unroll
        for (int f = 0; f < 4; ++f) {
            af[f] = *(const s8b*)(As + (wm + f * 16 + lr) * 32 + kb * 8);
            bf[f] = *(const s8b*)(Bs + (wn + f * 16 + lr) * 32 + kb * 8);
        }
        #pragma unroll
        for (int i = 0; i < 4; ++i)
            #pragma unroll
            for (int j = 0; j < 4; ++j)
                acc[i][j] = __builtin_amdgcn_mfma_f32_16x16x32_bf16(af[i], bf[j], acc[i][j], 0, 0, 0);
        __syncthreads();
    }

    // epilogue: C/D layout col=lane&15, row=(lane>>4)*4+reg  [verified m89/m91]
    #pragma unroll
    for (int i = 0; i < 4; ++i) {
        #pragma unroll
        for (int j = 0; j < 4; ++j) {
            #pragma unroll
            for (int r = 0; r < 4; ++r) {
                int m = m0 + wm + i * 16 + kb * 4 + r;
                int n = n0 + wn + j * 16 + lr;
                float val = acc[i][j][r] + (bias ? bias[n] : 0.0f);
                if (MODE != 2) C[(long)m * Nw + n] = val;
                if (MODE == 1) {
                    __hip_bfloat16 hi, lo; split_bf16(val, hi, lo);
                    long b = (long)m * (2 * Nw) + n;
                    P[b] = hi; P[b + Nw] = lo;
                }
                if (MODE == 2) {
                    __hip_bfloat16 hi, lo; split_bf16(val, hi, lo);
                    int bb = m >> 9, rr = m & 511;
                    long base = ((long)bb * Nw + n) * 1024;
                    P[base + rr] = hi; P[base + 512 + rr] = lo;
                }
            }
        }
    }
}

// ---------------- pack helpers ----------------
// row pack: src (M x K f32) -> dst (M x 2K bf16) [hi|lo]; K = 1<<kshift
__global__ __launch_bounds__(256) void pst_pack_rows(
    const float* __restrict__ src, __hip_bfloat16* __restrict__ dst, int kshift)
{
    long i = (long)blockIdx.x * 256 + threadIdx.x;
    int K = 1 << kshift;
    long m = i >> kshift; int k = (int)(i & (K - 1));
    float v = src[i];
    __hip_bfloat16 hi, lo; split_bf16(v, hi, lo);
    long b = (m << (kshift + 1)) + k;
    dst[b] = hi; dst[b + K] = lo;
}

// weight transpose pack: W (K x N f32) -> dst (N x 2K bf16) [hi|lo]
__global__ __launch_bounds__(256) void pst_packT_w(
    const float* __restrict__ W, __hip_bfloat16* __restrict__ dst, int K, int N, long total)
{
    long i = (long)blockIdx.x * 256 + threadIdx.x;
    if (i >= total) return;
    int k = (int)(i / N), n = (int)(i - (long)k * N);
    float v = W[i];
    __hip_bfloat16 hi, lo; split_bf16(v, hi, lo);
    long b = (long)n * (2 * K) + k;
    dst[b] = hi; dst[b + K] = lo;
}

// combined bias: out[n] = b2[n] + sum_k b1[k] * W2[k][n]   (1024x1024)
__global__ __launch_bounds__(256) void pst_bias_comb(
    const float* __restrict__ b1, const float* __restrict__ W2,
    const float* __restrict__ b2, float* __restrict__ out)
{
    int n = blockIdx.x * 256 + threadIdx.x;
    float s = b2[n];
    for (int k2 = 0; k2 < PDBIG; ++k2)
        s = fmaf(b1[k2], W2[(long)k2 * PDBIG + n], s);
    out[n] = s;
}

// ---------------- mask: sum|e| == 0 ----------------
__global__ __launch_bounds__(256) void pst_mask_kernel(
    const float* __restrict__ e, float* __restrict__ mask)
{
    int r = blockIdx.x;
    int tid = threadIdx.x;
    __shared__ float red[256];
    float s = 0.0f;
    for (int i = tid; i < PDBIG; i += 256)
        s += fabsf(e[(long)r * PDBIG + i]);
    float tot = block_sum256(s, red, tid);
    if (tid == 0) mask[r] = (tot == 0.0f) ? 1.0f : 0.0f;
}

// ---------------- scores -> softmax -> mean heads -> *w -> renorm -> A ----------------
__global__ __launch_bounds__(256) void pst_attnA_kernel(
    const float* __restrict__ q, const float* __restrict__ k,
    const float* __restrict__ mask, const float* __restrict__ features,
    float* __restrict__ A, int bGlobBase)
{
    int blk = blockIdx.x;
    int bLoc = blk >> 7;
    int q0 = (blk & 127) << 2;
    int tid = threadIdx.x;
    __shared__ float qs[4][PDBIG];
    __shared__ float sc[4][PN];
    __shared__ float pacc[4][PN];
    __shared__ float wm[PN];
    __shared__ float red[256];

    long qbase = ((long)(bLoc * PN + q0)) * PDBIG;
    for (int i = tid; i < 4 * PDBIG; i += 256)
        qs[i >> 10][i & (PDBIG - 1)] = q[qbase + i];
    int bGlob = bGlobBase + bLoc;
    for (int c = tid; c < PN; c += 256) {
        wm[c] = features[(((long)bGlob * PN) + c) * PFEA];
        pacc[0][c] = 0.0f; pacc[1][c] = 0.0f; pacc[2][c] = 0.0f; pacc[3][c] = 0.0f;
    }
    __syncthreads();

    const float scale = 0.0625f;
    float mk0 = mask[bLoc * PN + tid];
    float mk1 = mask[bLoc * PN + tid + 256];

    for (int h = 0; h < PH; ++h) {
        #pragma unroll
        for (int cc = 0; cc < 2; ++cc) {
            int c = tid + cc * 256;
            const float4* krow = (const float4*)(k + ((long)(bLoc * PN + c)) * PDBIG + h * PDD);
            const float4* q0p = (const float4*)&qs[0][h * PDD];
            const float4* q1p = (const float4*)&qs[1][h * PDD];
            const float4* q2p = (const float4*)&qs[2][h * PDD];
            const float4* q3p = (const float4*)&qs[3][h * PDD];
            float s0 = 0, s1 = 0, s2 = 0, s3 = 0;
            #pragma unroll 2
            for (int i = 0; i < PDD / 4; ++i) {
                float4 kv = krow[i];
                float4 a0 = q0p[i], a1 = q1p[i], a2 = q2p[i], a3 = q3p[i];
                s0 = fmaf(a0.x, kv.x, s0); s0 = fmaf(a0.y, kv.y, s0);
                s0 = fmaf(a0.z, kv.z, s0); s0 = fmaf(a0.w, kv.w, s0);
                s1 = fmaf(a1.x, kv.x, s1); s1 = fmaf(a1.y, kv.y, s1);
                s1 = fmaf(a1.z, kv.z, s1); s1 = fmaf(a1.w, kv.w, s1);
                s2 = fmaf(a2.x, kv.x, s2); s2 = fmaf(a2.y, kv.y, s2);
                s2 = fmaf(a2.z, kv.z, s2); s2 = fmaf(a2.w, kv.w, s2);
                s3 = fmaf(a3.x, kv.x, s3); s3 = fmaf(a3.y, kv.y, s3);
                s3 = fmaf(a3.z, kv.z, s3); s3 = fmaf(a3.w, kv.w, s3);
            }
            float mk = (cc == 0) ? mk0 : mk1;
            bool bad = (mk != 0.0f);
            sc[0][c] = bad ? -1e9f : s0 * scale;
            sc[1][c] = bad ? -1e9f : s1 * scale;
            sc[2][c] = bad ? -1e9f : s2 * scale;
            sc[3][c] = bad ? -1e9f : s3 * scale;
        }
        __syncthreads();
        for (int j = 0; j < 4; ++j) {
            float v0 = sc[j][tid], v1 = sc[j][tid + 256];
            float mx = block_max256(fmaxf(v0, v1), red, tid);
            float e0 = expf(v0 - mx), e1 = expf(v1 - mx);
            float ssum = block_sum256(e0 + e1, red, tid);
            float inv = 1.0f / ssum;
            pacc[j][tid] += e0 * inv;
            pacc[j][tid + 256] += e1 * inv;
        }
        __syncthreads();
    }
    for (int j = 0; j < 4; ++j) {
        float a0 = pacc[j][tid] * wm[tid];
        float a1 = pacc[j][tid + 256] * wm[tid + 256];
        float rs = block_sum256(a0 + a1, red, tid);
        float inv = 1.0f / rs;
        long row = (long)(bLoc * PN + q0 + j) * PN;
        A[row + tid] = a0 * inv;
        A[row + tid + 256] = a1 * inv;
    }
}

// ---------------- xe = LN(e + softplus(att)) (in place over e) ----------------
__global__ __launch_bounds__(256) void pst_spln_kernel(
    const float* __restrict__ att, float* __restrict__ e,
    const float* __restrict__ g, const float* __restrict__ b)
{
    int r = blockIdx.x;
    int tid = threadIdx.x;
    __shared__ float red[256];
    float v[4];
    float s = 0.0f;
    #pragma unroll
    for (int j = 0; j < 4; ++j) {
        int i = tid + j * 256;
        float a = att[(long)r * PDBIG + i];
        float sp = (a > 20.0f) ? a : log1pf(expf(a));
        v[j] = e[(long)r * PDBIG + i] + sp;
        s += v[j];
    }
    float mean = block_sum256(s, red, tid) * (1.0f / PDBIG);
    float vs = 0.0f;
    #pragma unroll
    for (int j = 0; j < 4; ++j) { float dv = v[j] - mean; vs += dv * dv; }
    float var = block_sum256(vs, red, tid) * (1.0f / PDBIG);
    float inv = rsqrtf(var + 1e-5f);
    #pragma unroll
    for (int j = 0; j < 4; ++j) {
        int i = tid + j * 256;
        e[(long)r * PDBIG + i] = (v[j] - mean) * inv * g[i] + b[i];
    }
}

// ---------------- pooled = LN(sum_n w*(x+x_init)); out = pooled@out_W + b ----------------
__global__ __launch_bounds__(256) void pst_pool_kernel(
    const float* __restrict__ features, const float* __restrict__ x,
    const float* __restrict__ x_init, const float* __restrict__ ln_g,
    const float* __restrict__ ln_b, const float* __restrict__ out_W,
    const float* __restrict__ out_b, float* __restrict__ out)
{
    int b = blockIdx.x;
    int tid = threadIdx.x;
    __shared__ float red[256];
    float acc = 0.0f;
    for (int n = 0; n < PN; ++n) {
        float w = features[(((long)b * PN) + n) * PFEA];
        long off = (((long)b * PN) + n) * PDD + tid;
        acc = fmaf(w, x[off] + x_init[off], acc);
    }
    float mean = block_sum256(acc, red, tid) * (1.0f / PDD);
    float dv = acc - mean;
    float var = block_sum256(dv * dv, red, tid) * (1.0f / PDD);
    float y = dv * rsqrtf(var + 1e-5f) * ln_g[tid] + ln_b[tid];
    float s = block_sum256(y * out_W[tid], red, tid);
    if (tid == 0) out[b] = s + out_b[0];
}

// ---------------- host ----------------
template<int MODE>
static void launch_gbf(const __hip_bfloat16* A, const __hip_bfloat16* B, const float* bias,
                       float* C, __hip_bfloat16* P, int M, int Nw, int K,
                       long sA, long sB, long sC, int batch, hipStream_t st)
{
    dim3 grid(Nw / 128, M / 128, batch);
    pst_gemm_bf16<MODE><<<grid, dim3(256), 0, st>>>(A, B, bias, C, P, K, Nw, sA, sB, sC);
}

extern "C" void kernel_launch(void* const* d_in, const int* in_sizes, int n_in,
                              void* d_out, int out_size, void* d_ws, size_t ws_size,
                              hipStream_t stream)
{
    const float* features  = (const float*)d_in[0];
    const float* atom_fea  = (const float*)d_in[1];
    const float* comp_W    = (const float*)d_in[2];
    const float* comp_b    = (const float*)d_in[3];
    const float* emb_W     = (const float*)d_in[4];
    const float* emb_b     = (const float*)d_in[5];
    const float* ln_g      = (const float*)d_in[6];
    const float* ln_b      = (const float*)d_in[7];
    const float* enc_emb_W = (const float*)d_in[8];
    const float* enc_emb_b = (const float*)d_in[9];
    const float* enc_Wq_W  = (const float*)d_in[10];
    const float* enc_Wq_b  = (const float*)d_in[11];
    const float* enc_Wk_W  = (const float*)d_in[12];
    const float* enc_Wk_b  = (const float*)d_in[13];
    const float* enc_Wv_W  = (const float*)d_in[14];
    const float* enc_Wv_b  = (const float*)d_in[15];
    const float* enc_inq_W = (const float*)d_in[16];
    const float* enc_inq_b = (const float*)d_in[17];
    const float* enc_ink_W = (const float*)d_in[18];
    const float* enc_ink_b = (const float*)d_in[19];
    const float* enc_ln_g  = (const float*)d_in[20];
    const float* enc_ln_b  = (const float*)d_in[21];
    const float* enc_out_W = (const float*)d_in[22];
    const float* enc_out_b = (const float*)d_in[23];
    const float* out_W     = (const float*)d_in[24];
    const float* out_b     = (const float*)d_in[25];

    // ----- workspace layout (units: floats) -----
    // persistent: x, x_init, weight packs, Wtmp, combined biases
    const size_t SZ_X     = (size_t)PB * PN * PDD;          // 8.39M
    const size_t SZ_WEMB  = (size_t)PDBIG * 2 * PDD / 2;    // bf16 1024x512 -> fl
    const size_t SZ_WBIG  = (size_t)PDBIG * 2 * PDBIG / 2;  // bf16 1024x2048 -> fl
    const size_t SZ_WOUT  = (size_t)PDD * 2 * PDBIG / 2;    // bf16 256x2048 -> fl
    size_t persist = 2 * SZ_X + 3 * (SZ_WEMB + 3 * SZ_WBIG + SZ_WOUT)
                   + (size_t)PDBIG * PDBIG + 6 * PDBIG;

    int CB = 16;
    while (CB > 1) {
        size_t M = (size_t)CB * PN;
        size_t chunk = M * (256 + 1024 + 1024 + 1024 + 1024 + 1024 + 512 + 512 + 1);
        if ((persist + chunk) * sizeof(float) <= ws_size) break;
        CB >>= 1;
    }
    const size_t M = (size_t)CB * PN;

    float* ws = (float*)d_ws;
    size_t off = 0;
    float* x      = ws + off; off += SZ_X;
    float* x_init = ws + off; off += SZ_X;
    __hip_bfloat16* WembT[PL]; __hip_bfloat16* WqcT[PL]; __hip_bfloat16* WkcT[PL];
    __hip_bfloat16* WvT[PL];  __hip_bfloat16* WoutT[PL];
    for (int l = 0; l < PL; ++l) {
        WembT[l] = (__hip_bfloat16*)(ws + off); off += SZ_WEMB;
        WqcT[l]  = (__hip_bfloat16*)(ws + off); off += SZ_WBIG;
        WkcT[l]  = (__hip_bfloat16*)(ws + off); off += SZ_WBIG;
        WvT[l]   = (__hip_bfloat16*)(ws + off); off += SZ_WBIG;
        WoutT[l] = (__hip_bfloat16*)(ws + off); off += SZ_WOUT;
    }
    float* Wtmp = ws + off; off += (size_t)PDBIG * PDBIG;
    float* bqc  = ws + off; off += 3 * PDBIG;
    float* bkc  = ws + off; off += 3 * PDBIG;
    // per-chunk
    __hip_bfloat16* xp    = (__hip_bfloat16*)(ws + off); off += M * 256;
    float* e              = ws + off;                    off += M * 1024;
    __hip_bfloat16* epack = (__hip_bfloat16*)(ws + off); off += M * 1024;
    float* q              = ws + off;                    off += M * 1024;  // also att
    float* k              = ws + off;                    off += M * 1024;
    __hip_bfloat16* vpT   = (__hip_bfloat16*)(ws + off); off += M * 1024;
    float* Abuf           = ws + off;                    off += M * 512;
    __hip_bfloat16* Apack = (__hip_bfloat16*)(ws + off); off += M * 512;
    float* maskb          = ws + off;                    off += M;

    // ----- precompute: combined q/k weights + all weight packs -----
    for (int l = 0; l < PL; ++l) {
        const size_t WS = (size_t)PDBIG * PDBIG;
        // Wqc = Wq @ inq ; bqc = bq @ inq + binq
        pst_gemm_f32<<<dim3(16, 16, 1), 256, 0, stream>>>(
            enc_Wq_W + l * WS, enc_inq_W + l * WS, nullptr, Wtmp,
            PDBIG, PDBIG, PDBIG, PDBIG, PDBIG, PDBIG);
        pst_packT_w<<<dim3((WS + 255) / 256), 256, 0, stream>>>(
            Wtmp, WqcT[l], PDBIG, PDBIG, (long)WS);
        pst_bias_comb<<<dim3(4), 256, 0, stream>>>(
            enc_Wq_b + l * PDBIG, enc_inq_W + l * WS, enc_inq_b + l * PDBIG, bqc + l * PDBIG);
        // Wkc = Wk @ ink ; bkc
        pst_gemm_f32<<<dim3(16, 16, 1), 256, 0, stream>>>(
            enc_Wk_W + l * WS, enc_ink_W + l * WS, nullptr, Wtmp,
            PDBIG, PDBIG, PDBIG, PDBIG, PDBIG, PDBIG);
        pst_packT_w<<<dim3((WS + 255) / 256), 256, 0, stream>>>(
            Wtmp, WkcT[l], PDBIG, PDBIG, (long)WS);
        pst_bias_comb<<<dim3(4), 256, 0, stream>>>(
            enc_Wk_b + l * PDBIG, enc_ink_W + l * WS, enc_ink_b + l * PDBIG, bkc + l * PDBIG);
        // direct packs
        const size_t WE = (size_t)PDD * PDBIG;
        pst_packT_w<<<dim3((WE + 255) / 256), 256, 0, stream>>>(
            enc_emb_W + l * WE, WembT[l], PDD, PDBIG, (long)WE);
        pst_packT_w<<<dim3((WS + 255) / 256), 256, 0, stream>>>(
            enc_Wv_W + l * WS, WvT[l], PDBIG, PDBIG, (long)WS);
        pst_packT_w<<<dim3((WE + 255) / 256), 256, 0, stream>>>(
            enc_out_W + l * WE, WoutT[l], PDBIG, PDD, (long)WE);
    }

    // ----- embedding -----
    pst_embed_kernel<<<dim3(PB * PN), 256, 0, stream>>>(
        features, atom_fea, comp_W, comp_b, emb_W, emb_b, ln_g, ln_b, x, x_init);

    // ----- encoder layers, chunked over batch -----
    for (int cb0 = 0; cb0 < PB; cb0 += CB) {
        float* xs = x + (size_t)cb0 * PN * PDD;
        const int Mi = (int)M;
        for (int l = 0; l < PL; ++l) {
            // xp = pack(xs)  [M x 2*256]
            pst_pack_rows<<<dim3(Mi * 256 / 256), 256, 0, stream>>>(xs, xp, 8);
            // e = xp @ WembT + b   (f32 + pack)
            launch_gbf<1>(xp, WembT[l], enc_emb_b + (size_t)l * PDBIG, e, epack,
                          Mi, PDBIG, PDD, 0, 0, 0, 1, stream);
            // q, k (combined weights), v (transposed pack only)
            launch_gbf<0>(epack, WqcT[l], bqc + (size_t)l * PDBIG, q, nullptr,
                          Mi, PDBIG, PDBIG, 0, 0, 0, 1, stream);
            launch_gbf<0>(epack, WkcT[l], bkc + (size_t)l * PDBIG, k, nullptr,
                          Mi, PDBIG, PDBIG, 0, 0, 0, 1, stream);
            launch_gbf<2>(epack, WvT[l], enc_Wv_b + (size_t)l * PDBIG, nullptr, vpT,
                          Mi, PDBIG, PDBIG, 0, 0, 0, 1, stream);
            // mask + attention weights
            pst_mask_kernel<<<dim3(Mi), 256, 0, stream>>>(e, maskb);
            pst_attnA_kernel<<<dim3(CB * 128), 256, 0, stream>>>(
                q, k, maskb, features, Abuf, cb0);
            // Apack = pack(Abuf)  [CB*512 x 2*512]
            pst_pack_rows<<<dim3(Mi * 512 / 256), 256, 0, stream>>>(Abuf, Apack, 9);
            // att = A @ v (batched) -> q buffer
            launch_gbf<0>(Apack, vpT, nullptr, q, nullptr,
                          PN, PDBIG, PN,
                          (long)PN * 1024, (long)PDBIG * 1024, (long)PN * PDBIG, CB, stream);
            // xe = LN(e + softplus(att)) in place; re-pack
            pst_spln_kernel<<<dim3(Mi), 256, 0, stream>>>(
                q, e, enc_ln_g + (size_t)l * PDBIG, enc_ln_b + (size_t)l * PDBIG);
            pst_pack_rows<<<dim3(Mi * 1024 / 256), 256, 0, stream>>>(e, epack, 10);
            // x = xe @ WoutT + b
            launch_gbf<0>(epack, WoutT[l], enc_out_b + (size_t)l * PDD, xs, nullptr,
                          Mi, PDD, PDBIG, 0, 0, 0, 1, stream);
        }
    }

    pst_pool_kernel<<<dim3(PB), 256, 0, stream>>>(
        features, x, x_init, ln_g, ln_b, out_W, out_b, (float*)d_out);
}

// Round 4
// 10454.736 us; speedup vs baseline: 2.9376x; 1.8616x over previous
//
#include <hip/hip_runtime.h>
#include <hip/hip_bf16.h>

// ---------------- problem constants ----------------
#define PB 64      // batch
#define PN 512     // set size
#define PFEA 102
#define PE 10
#define PDD 256    // d
#define PH 4
#define PDBIG 1024 // D = d*H
#define PL 3
#define PNDIST 100

typedef __attribute__((ext_vector_type(8))) short s8b;   // 8 bf16 (4 VGPRs)
typedef __attribute__((ext_vector_type(4))) float f4;    // 4 fp32 acc

typedef __attribute__((address_space(1))) const void gvoid_t;
typedef __attribute__((address_space(3))) void lvoid_t;
#define GLDS16(g, s) __builtin_amdgcn_global_load_lds((gvoid_t*)(g), (lvoid_t*)(s), 16, 0, 0)

__device__ __forceinline__ void split_bf16(float v, __hip_bfloat16& hi, __hip_bfloat16& lo) {
    hi = __float2bfloat16(v);
    lo = __float2bfloat16(v - __bfloat162float(hi));
}

// ---------------- reduction helpers (shfl-based, wave64) ----------------
__device__ __forceinline__ float block_sum1(float v, float* red, int tid) {
    #pragma unroll
    for (int off = 32; off >= 1; off >>= 1) v += __shfl_xor(v, off);
    __syncthreads();
    if ((tid & 63) == 0) red[tid >> 6] = v;
    __syncthreads();
    return red[0] + red[1] + red[2] + red[3];
}

template<int NR, bool MAXOP>
__device__ __forceinline__ void block_redN(float* v, float* red, int tid) {
    #pragma unroll
    for (int off = 32; off >= 1; off >>= 1) {
        #pragma unroll
        for (int r = 0; r < NR; ++r) {
            float o = __shfl_xor(v[r], off);
            v[r] = MAXOP ? fmaxf(v[r], o) : (v[r] + o);
        }
    }
    __syncthreads();
    if ((tid & 63) == 0) {
        #pragma unroll
        for (int r = 0; r < NR; ++r) red[(tid >> 6) * NR + r] = v[r];
    }
    __syncthreads();
    #pragma unroll
    for (int r = 0; r < NR; ++r) {
        float a = red[r], b = red[NR + r], c = red[2 * NR + r], d = red[3 * NR + r];
        v[r] = MAXOP ? fmaxf(fmaxf(a, b), fmaxf(c, d)) : ((a + b) + (c + d));
    }
    __syncthreads();
}

// ---------------- precompute kernels ----------------
__global__ __launch_bounds__(256) void pst_atomproj(
    const float* __restrict__ atom_fea, const float* __restrict__ comp_W,
    float* __restrict__ atomP)
{
    int a = blockIdx.x, tid = threadIdx.x;
    __shared__ float af[92];
    if (tid < 92) af[tid] = atom_fea[a * 92 + tid];
    __syncthreads();
    float s = 0.0f;
    #pragma unroll 4
    for (int k = 0; k < 92; ++k) s = fmaf(af[k], comp_W[k * PDD + tid], s);
    atomP[a * PDD + tid] = s;
}

__global__ __launch_bounds__(256) void pst_embW_reduce(
    const float* __restrict__ emb_W, float* __restrict__ S0, float* __restrict__ S1)
{
    int f = blockIdx.x, tid = threadIdx.x;
    float s0 = 0.0f, s1 = 0.0f;
    #pragma unroll
    for (int t = 0; t < PE; ++t) {
        float w = emb_W[(f * PE + t) * PDD + tid];
        float tf = (float)t / (float)PE;
        s0 += w;
        s1 = fmaf(2.0f * tf, w, s1);
    }
    S0[f * PDD + tid] = s0;
    S1[f * PDD + tid] = s1;
}

__global__ __launch_bounds__(256) void pst_embW_const(
    const float* __restrict__ emb_W, const float* __restrict__ comp_b,
    const float* __restrict__ emb_b, float* __restrict__ Cv)
{
    int tid = threadIdx.x;
    float s = comp_b[tid] + emb_b[tid];
    for (int m = 0; m < PNDIST * PE; ++m) {
        float tf = (float)(m % PE) / (float)PE;
        s = fmaf(tf * tf, emb_W[m * PDD + tid], s);
    }
    Cv[tid] = s;
}

// ---------------- embed: 4 rows/block ----------------
__global__ __launch_bounds__(256) void pst_embed4(
    const float* __restrict__ features, const float* __restrict__ atomP,
    const float* __restrict__ S0, const float* __restrict__ S1,
    const float* __restrict__ Cv, const float* __restrict__ ln_g,
    const float* __restrict__ ln_b, float* __restrict__ x, float* __restrict__ x_init)
{
    int r0 = blockIdx.x * 4, tid = threadIdx.x;
    __shared__ float uv[4][PNDIST];
    __shared__ int idxs[4];
    __shared__ float red[16];
    // FIX(R3): grid-stride loop — 400 entries, 256 threads (R2 dropped 144 entries)
    for (int m = tid; m < 4 * PNDIST; m += 256) {
        int r = m / PNDIST, f = m - r * PNDIST;
        uv[r][f] = 1.0f - features[(long)(r0 + r) * PFEA + 1 + f];
    }
    if (tid < 4) idxs[tid] = (int)features[(long)(r0 + tid) * PFEA + PFEA - 1];
    __syncthreads();

    float acc[4];
    float cv = Cv[tid];
    #pragma unroll
    for (int r = 0; r < 4; ++r) acc[r] = cv + atomP[idxs[r] * PDD + tid];
    for (int f = 0; f < PNDIST; ++f) {
        float s0 = S0[f * PDD + tid], s1 = S1[f * PDD + tid];
        #pragma unroll
        for (int r = 0; r < 4; ++r) {
            float u = uv[r][f];
            acc[r] = fmaf(u, fmaf(u, s0, s1), acc[r]);
        }
    }
    float mean[4];
    #pragma unroll
    for (int r = 0; r < 4; ++r) mean[r] = acc[r];
    block_redN<4, false>(mean, red, tid);
    float var[4], dv[4];
    #pragma unroll
    for (int r = 0; r < 4; ++r) { mean[r] *= (1.0f / PDD); dv[r] = acc[r] - mean[r]; var[r] = dv[r] * dv[r]; }
    block_redN<4, false>(var, red, tid);
    #pragma unroll
    for (int r = 0; r < 4; ++r) {
        float y = dv[r] * rsqrtf(var[r] * (1.0f / PDD) + 1e-5f) * ln_g[tid] + ln_b[tid];
        long o = (long)(r0 + r) * PDD + tid;
        x[o] = y;
        x_init[o] = y;
    }
}

// ---------------- bf16 split-K MFMA GEMM ----------------
// A pack: M x 2K [hi|lo] row-major; B pack: N x 2K [hi|lo] (= B^T) row-major.
// computes Ah@Bh + Al@Bh + Ah@Bl via K-loop over 3K with block remap.
// MODE 0: C f32 (ldc=Nw), batched via z.
// MODE 1: C f32 + P row-pack (M x 2*Nw).
// MODE 3: qkv routing: n<1024 -> C=q f32; n<2048 -> kT f32 transposed
//         [bb][1024][512]; else -> vpT bf16 transposed pack [bb][n][hi512|lo512].
template<int MODE>
__global__ __launch_bounds__(256) void pst_gemm_bf16(
    const __hip_bfloat16* __restrict__ Ap, const __hip_bfloat16* __restrict__ Bp,
    const float* __restrict__ bias, float* __restrict__ C,
    __hip_bfloat16* __restrict__ P, float* __restrict__ kT,
    __hip_bfloat16* __restrict__ vpT,
    int K, int Nw, long strideA, long strideB, long strideC)
{
    const int lda = 2 * K, ldb = 2 * K;
    int bz = blockIdx.z;
    Ap += (long)bz * strideA; Bp += (long)bz * strideB;
    if (MODE == 0) C += (long)bz * strideC;

    __shared__ __hip_bfloat16 As[128 * 32];
    __shared__ __hip_bfloat16 Bs[128 * 32];

    int tid = threadIdx.x;
    int w = tid >> 6, l = tid & 63;
    int r4 = tid >> 2;
    int c8 = (tid & 3) * 8;
    int m0 = blockIdx.y * 128, n0 = blockIdx.x * 128;
    int lr = l & 15, kb = l >> 4;
    int wm = (w >> 1) * 64, wn = (w & 1) * 64;

    f4 acc[4][4] = {};

    const int K3 = 3 * K;
    for (int k0 = 0; k0 < K3; k0 += 32) {
        int kA = (k0 < 2 * K) ? k0 : k0 - 2 * K;   // hi, lo, hi
        int kB = (k0 < K) ? k0 : k0 - K;           // hi, hi, lo
        const __hip_bfloat16* ga = Ap + (long)(m0 + r4) * lda + kA + c8;
        const __hip_bfloat16* gb = Bp + (long)(n0 + r4) * ldb + kB + c8;
        GLDS16(ga,             As + w * 512);
        GLDS16(ga + 64L * lda, As + 2048 + w * 512);
        GLDS16(gb,             Bs + w * 512);
        GLDS16(gb + 64L * ldb, Bs + 2048 + w * 512);
        __syncthreads();

        s8b af[4], bf[4];
        #pragma unroll
        for (int f = 0; f < 4; ++f) {
            af[f] = *(const s8b*)(As + (wm + f * 16 + lr) * 32 + kb * 8);
            bf[f] = *(const s8b*)(Bs + (wn + f * 16 + lr) * 32 + kb * 8);
        }
        #pragma unroll
        for (int i = 0; i < 4; ++i)
            #pragma unroll
            for (int j = 0; j < 4; ++j)
                acc[i][j] = __builtin_amdgcn_mfma_f32_16x16x32_bf16(af[i], bf[j], acc[i][j], 0, 0, 0);
        __syncthreads();
    }

    int region = (MODE == 3) ? (n0 >> 10) : 0;

    // C/D layout: col=lane&15, row=(lane>>4)*4+reg [verified m89/m91]
    #pragma unroll
    for (int i = 0; i < 4; ++i) {
        #pragma unroll
        for (int j = 0; j < 4; ++j) {
            #pragma unroll
            for (int r = 0; r < 4; ++r) {
                int m = m0 + wm + i * 16 + kb * 4 + r;
                int n = n0 + wn + j * 16 + lr;
                float val = acc[i][j][r] + (bias ? bias[n] : 0.0f);
                if (MODE == 0) {
                    C[(long)m * Nw + n] = val;
                } else if (MODE == 1) {
                    C[(long)m * Nw + n] = val;
                    __hip_bfloat16 hi, lo; split_bf16(val, hi, lo);
                    long b = (long)m * (2 * Nw) + n;
                    P[b] = hi; P[b + Nw] = lo;
                } else { // MODE 3
                    int bb = m >> 9, rr = m & 511;
                    if (region == 0) {
                        C[(long)m * PDBIG + n] = val;
                    } else if (region == 1) {
                        kT[((long)bb * PDBIG + (n - 1024)) * PN + rr] = val;
                    } else {
                        __hip_bfloat16 hi, lo; split_bf16(val, hi, lo);
                        long base = ((long)bb * PDBIG + (n - 2048)) * 1024;
                        vpT[base + rr] = hi; vpT[base + 512 + rr] = lo;
                    }
                }
            }
        }
    }
}

// ---------------- pack helpers ----------------
__global__ __launch_bounds__(256) void pst_pack_rows(
    const float* __restrict__ src, __hip_bfloat16* __restrict__ dst, int kshift)
{
    long i = (long)blockIdx.x * 256 + threadIdx.x;
    int K = 1 << kshift;
    long m = i >> kshift; int k = (int)(i & (K - 1));
    float v = src[i];
    __hip_bfloat16 hi, lo; split_bf16(v, hi, lo);
    long b = (m << (kshift + 1)) + k;
    dst[b] = hi; dst[b + K] = lo;
}

__global__ __launch_bounds__(256) void pst_packT_w(
    const float* __restrict__ W, __hip_bfloat16* __restrict__ dst, int K, int N, long total)
{
    long i = (long)blockIdx.x * 256 + threadIdx.x;
    if (i >= total) return;
    int k = (int)(i / N), n = (int)(i - (long)k * N);
    float v = W[i];
    __hip_bfloat16 hi, lo; split_bf16(v, hi, lo);
    long b = (long)n * (2 * K) + k;
    dst[b] = hi; dst[b + K] = lo;
}

__global__ __launch_bounds__(256) void pst_bias_comb(
    const float* __restrict__ b1, const float* __restrict__ W2,
    const float* __restrict__ b2, float* __restrict__ out)
{
    int n = blockIdx.x * 256 + threadIdx.x;
    float s = b2[n];
    for (int k2 = 0; k2 < PDBIG; ++k2)
        s = fmaf(b1[k2], W2[(long)k2 * PDBIG + n], s);
    out[n] = s;
}

__global__ __launch_bounds__(256) void pst_copy1024(
    const float* __restrict__ src, float* __restrict__ dst)
{
    int i = blockIdx.x * 256 + threadIdx.x;
    dst[i] = src[i];
}

// ---------------- mask ----------------
__global__ __launch_bounds__(256) void pst_mask_kernel(
    const float* __restrict__ e, float* __restrict__ mask)
{
    int r = blockIdx.x, tid = threadIdx.x;
    __shared__ float red[4];
    float s = 0.0f;
    #pragma unroll
    for (int j = 0; j < 4; ++j) s += fabsf(e[(long)r * PDBIG + tid + j * 256]);
    float tot = block_sum1(s, red, tid);
    if (tid == 0) mask[r] = (tot == 0.0f) ? 1.0f : 0.0f;
}

// ---------------- attention A ----------------
__global__ __launch_bounds__(256) void pst_attnA(
    const float* __restrict__ q, const float* __restrict__ kT,
    const float* __restrict__ maskb, const float* __restrict__ features,
    __hip_bfloat16* __restrict__ Apack, int bGlobBase)
{
    int blk = blockIdx.x;
    int bLoc = blk >> 6;
    int q0 = (blk & 63) << 3;
    int tid = threadIdx.x;
    __shared__ float qs[8][PDBIG];
    __shared__ float wm[PN];
    __shared__ float red[32];

    long qbase = ((long)bLoc * PN + q0) * PDBIG;
    const float4* qsrc = (const float4*)(q + qbase);
    for (int i = tid; i < 8 * PDBIG / 4; i += 256) ((float4*)qs)[i] = qsrc[i];
    int bGlob = bGlobBase + bLoc;
    for (int c = tid; c < PN; c += 256) wm[c] = features[((long)bGlob * PN + c) * PFEA];
    __syncthreads();

    bool bad0 = maskb[bLoc * PN + tid] != 0.0f;
    bool bad1 = maskb[bLoc * PN + tid + 256] != 0.0f;
    const float scale = 0.0625f;   // 1/sqrt(256)
    float pacc[8][2] = {};

    for (int h = 0; h < PH; ++h) {
        const float* kb = kT + ((long)bLoc * PDBIG + h * PDD) * PN;
        float s[8][2] = {};
        for (int i4 = 0; i4 < PDD / 4; ++i4) {
            float4 qv[8];
            #pragma unroll
            for (int r = 0; r < 8; ++r)
                qv[r] = *(const float4*)&qs[r][h * PDD + i4 * 4];
            #pragma unroll
            for (int ii = 0; ii < 4; ++ii) {
                int i = i4 * 4 + ii;
                float kv0 = kb[(long)i * PN + tid];
                float kv1 = kb[(long)i * PN + tid + 256];
                #pragma unroll
                for (int r = 0; r < 8; ++r) {
                    float qvv = (ii == 0) ? qv[r].x : (ii == 1) ? qv[r].y : (ii == 2) ? qv[r].z : qv[r].w;
                    s[r][0] = fmaf(qvv, kv0, s[r][0]);
                    s[r][1] = fmaf(qvv, kv1, s[r][1]);
                }
            }
        }
        float mrow[8];
        #pragma unroll
        for (int r = 0; r < 8; ++r) {
            float a = bad0 ? -1e9f : s[r][0] * scale;
            float b = bad1 ? -1e9f : s[r][1] * scale;
            s[r][0] = a; s[r][1] = b;
            mrow[r] = fmaxf(a, b);
        }
        block_redN<8, true>(mrow, red, tid);
        float srow[8];
        #pragma unroll
        for (int r = 0; r < 8; ++r) {
            float e0 = __expf(s[r][0] - mrow[r]);
            float e1 = __expf(s[r][1] - mrow[r]);
            s[r][0] = e0; s[r][1] = e1;
            srow[r] = e0 + e1;
        }
        block_redN<8, false>(srow, red, tid);
        #pragma unroll
        for (int r = 0; r < 8; ++r) {
            float inv = 1.0f / srow[r];
            pacc[r][0] += s[r][0] * inv;
            pacc[r][1] += s[r][1] * inv;
        }
    }

    float arow[8];
    #pragma unroll
    for (int r = 0; r < 8; ++r) {
        pacc[r][0] *= wm[tid];
        pacc[r][1] *= wm[tid + 256];
        arow[r] = pacc[r][0] + pacc[r][1];
    }
    block_redN<8, false>(arow, red, tid);
    #pragma unroll
    for (int r = 0; r < 8; ++r) {
        float inv = 1.0f / arow[r];
        long rowb = ((long)bLoc * PN + q0 + r) * 1024;
        __hip_bfloat16 hi, lo;
        split_bf16(pacc[r][0] * inv, hi, lo);
        Apack[rowb + tid] = hi; Apack[rowb + 512 + tid] = lo;
        split_bf16(pacc[r][1] * inv, hi, lo);
        Apack[rowb + tid + 256] = hi; Apack[rowb + 512 + tid + 256] = lo;
    }
}

// ---------------- xe = LN(e + softplus(att)) -> epack ----------------
__global__ __launch_bounds__(256) void pst_spln(
    const float* __restrict__ att, const float* __restrict__ e,
    __hip_bfloat16* __restrict__ ep, const float* __restrict__ g,
    const float* __restrict__ bb)
{
    int r = blockIdx.x, tid = threadIdx.x;
    __shared__ float red[4];
    float v[4];
    float s = 0.0f;
    #pragma unroll
    for (int j = 0; j < 4; ++j) {
        int i = tid + j * 256;
        float a = att[(long)r * PDBIG + i];
        float sp = (a > 20.0f) ? a : log1pf(expf(a));
        v[j] = e[(long)r * PDBIG + i] + sp;
        s += v[j];
    }
    float mean = block_sum1(s, red, tid) * (1.0f / PDBIG);
    float vs = 0.0f;
    #pragma unroll
    for (int j = 0; j < 4; ++j) { float dv = v[j] - mean; vs += dv * dv; }
    float var = block_sum1(vs, red, tid) * (1.0f / PDBIG);
    float inv = rsqrtf(var + 1e-5f);
    #pragma unroll
    for (int j = 0; j < 4; ++j) {
        int i = tid + j * 256;
        float y = (v[j] - mean) * inv * g[i] + bb[i];
        __hip_bfloat16 hi, lo; split_bf16(y, hi, lo);
        ep[(long)r * 2048 + i] = hi;
        ep[(long)r * 2048 + 1024 + i] = lo;
    }
}

// ---------------- pool (2-phase) ----------------
__global__ __launch_bounds__(256) void pst_pool1(
    const float* __restrict__ features, const float* __restrict__ x,
    const float* __restrict__ xi, float* __restrict__ partial)
{
    int p = blockIdx.x, b = blockIdx.y, tid = threadIdx.x;
    float acc = 0.0f;
    for (int n = p * 64; n < p * 64 + 64; ++n) {
        float w = features[((long)b * PN + n) * PFEA];
        long off = ((long)b * PN + n) * PDD + tid;
        acc = fmaf(w, x[off] + xi[off], acc);
    }
    partial[((long)b * 8 + p) * PDD + tid] = acc;
}

__global__ __launch_bounds__(256) void pst_pool2(
    const float* __restrict__ partial, const float* __restrict__ ln_g,
    const float* __restrict__ ln_b, const float* __restrict__ out_W,
    const float* __restrict__ out_b, float* __restrict__ out)
{
    int b = blockIdx.x, tid = threadIdx.x;
    __shared__ float red[4];
    float acc = 0.0f;
    #pragma unroll
    for (int p = 0; p < 8; ++p) acc += partial[((long)b * 8 + p) * PDD + tid];
    float mean = block_sum1(acc, red, tid) * (1.0f / PDD);
    float dv = acc - mean;
    float var = block_sum1(dv * dv, red, tid) * (1.0f / PDD);
    float y = dv * rsqrtf(var + 1e-5f) * ln_g[tid] + ln_b[tid];
    float s = block_sum1(y * out_W[tid], red, tid);
    if (tid == 0) out[b] = s + out_b[0];
}

// ---------------- host ----------------
template<int MODE>
static void launch_gbf(const __hip_bfloat16* A, const __hip_bfloat16* B, const float* bias,
                       float* C, __hip_bfloat16* P, float* kT, __hip_bfloat16* vp,
                       int M, int Nw, int K, long sA, long sB, long sC, int batch,
                       hipStream_t st)
{
    dim3 grid(Nw / 128, M / 128, batch);
    pst_gemm_bf16<MODE><<<grid, dim3(256), 0, st>>>(A, B, bias, C, P, kT, vp, K, Nw, sA, sB, sC);
}

extern "C" void kernel_launch(void* const* d_in, const int* in_sizes, int n_in,
                              void* d_out, int out_size, void* d_ws, size_t ws_size,
                              hipStream_t stream)
{
    const float* features  = (const float*)d_in[0];
    const float* atom_fea  = (const float*)d_in[1];
    const float* comp_W    = (const float*)d_in[2];
    const float* comp_b    = (const float*)d_in[3];
    const float* emb_W     = (const float*)d_in[4];
    const float* emb_b     = (const float*)d_in[5];
    const float* ln_g      = (const float*)d_in[6];
    const float* ln_b      = (const float*)d_in[7];
    const float* enc_emb_W = (const float*)d_in[8];
    const float* enc_emb_b = (const float*)d_in[9];
    const float* enc_Wq_W  = (const float*)d_in[10];
    const float* enc_Wq_b  = (const float*)d_in[11];
    const float* enc_Wk_W  = (const float*)d_in[12];
    const float* enc_Wk_b  = (const float*)d_in[13];
    const float* enc_Wv_W  = (const float*)d_in[14];
    const float* enc_Wv_b  = (const float*)d_in[15];
    const float* enc_inq_W = (const float*)d_in[16];
    const float* enc_inq_b = (const float*)d_in[17];
    const float* enc_ink_W = (const float*)d_in[18];
    const float* enc_ink_b = (const float*)d_in[19];
    const float* enc_ln_g  = (const float*)d_in[20];
    const float* enc_ln_b  = (const float*)d_in[21];
    const float* enc_out_W = (const float*)d_in[22];
    const float* enc_out_b = (const float*)d_in[23];
    const float* out_W     = (const float*)d_in[24];
    const float* out_b     = (const float*)d_in[25];

    // ----- workspace layout (floats) -----
    const size_t SZ_X = (size_t)PB * PN * PDD;
    float* ws = (float*)d_ws;
    size_t off = 0;
    float* x      = ws + off; off += SZ_X;
    float* x_init = ws + off; off += SZ_X;
    __hip_bfloat16* WembT[PL]; __hip_bfloat16* WqkvT[PL]; __hip_bfloat16* WoutT[PL];
    float* bqkv[PL];
    for (int l = 0; l < PL; ++l) {
        WembT[l] = (__hip_bfloat16*)(ws + off); off += (size_t)1024 * 512 / 2;
        WqkvT[l] = (__hip_bfloat16*)(ws + off); off += (size_t)3072 * 2048 / 2;
        WoutT[l] = (__hip_bfloat16*)(ws + off); off += (size_t)256 * 2048 / 2;
        bqkv[l]  = ws + off; off += 3072;
    }
    float* Wtmp = ws + off; off += (size_t)1024 * 1024;
    __hip_bfloat16* pA = (__hip_bfloat16*)(ws + off); off += (size_t)1024 * 2048 / 2;
    __hip_bfloat16* pB = (__hip_bfloat16*)(ws + off); off += (size_t)1024 * 2048 / 2;
    float* atomP = ws + off; off += (size_t)100 * PDD;
    float* S0v   = ws + off; off += (size_t)PNDIST * PDD;
    float* S1v   = ws + off; off += (size_t)PNDIST * PDD;
    float* Cv    = ws + off; off += PDD;
    float* partial = ws + off; off += (size_t)PB * 8 * PDD;
    size_t persistf = off;

    int CB = 64;
    while (CB > 1) {
        size_t M = (size_t)CB * PN;
        size_t chunk = M * (256 + 1024 + 1024 + 1024 + 1024 + 1024 + 512 + 1);
        if ((persistf + chunk) * sizeof(float) <= ws_size) break;
        CB >>= 1;
    }
    const size_t M = (size_t)CB * PN;

    __hip_bfloat16* xp    = (__hip_bfloat16*)(ws + off); off += M * 256;
    float* e              = ws + off;                    off += M * 1024;
    __hip_bfloat16* epack = (__hip_bfloat16*)(ws + off); off += M * 1024;
    float* q              = ws + off;                    off += M * 1024;   // also att
    float* kT             = ws + off;                    off += M * 1024;
    __hip_bfloat16* vpT   = (__hip_bfloat16*)(ws + off); off += M * 1024;
    __hip_bfloat16* Apack = (__hip_bfloat16*)(ws + off); off += M * 512;
    float* maskb          = ws + off;                    off += M;

    // ----- precompute: embed reductions -----
    pst_atomproj<<<dim3(100), 256, 0, stream>>>(atom_fea, comp_W, atomP);
    pst_embW_reduce<<<dim3(PNDIST), 256, 0, stream>>>(emb_W, S0v, S1v);
    pst_embW_const<<<dim3(1), 256, 0, stream>>>(emb_W, comp_b, emb_b, Cv);

    // ----- precompute: weight packs / combined q,k -----
    const size_t WS = (size_t)PDBIG * PDBIG;
    const size_t WE = (size_t)PDD * PDBIG;
    for (int l = 0; l < PL; ++l) {
        pst_pack_rows<<<dim3(WS / 256), 256, 0, stream>>>(enc_Wq_W + l * WS, pA, 10);
        pst_packT_w<<<dim3((WS + 255) / 256), 256, 0, stream>>>(enc_inq_W + l * WS, pB, 1024, 1024, (long)WS);
        launch_gbf<0>(pA, pB, nullptr, Wtmp, nullptr, nullptr, nullptr, 1024, 1024, 1024, 0, 0, 0, 1, stream);
        pst_packT_w<<<dim3((WS + 255) / 256), 256, 0, stream>>>(Wtmp, WqkvT[l], 1024, 1024, (long)WS);
        pst_bias_comb<<<dim3(4), 256, 0, stream>>>(enc_Wq_b + l * PDBIG, enc_inq_W + l * WS,
                                                   enc_inq_b + l * PDBIG, bqkv[l]);
        pst_pack_rows<<<dim3(WS / 256), 256, 0, stream>>>(enc_Wk_W + l * WS, pA, 10);
        pst_packT_w<<<dim3((WS + 255) / 256), 256, 0, stream>>>(enc_ink_W + l * WS, pB, 1024, 1024, (long)WS);
        launch_gbf<0>(pA, pB, nullptr, Wtmp, nullptr, nullptr, nullptr, 1024, 1024, 1024, 0, 0, 0, 1, stream);
        pst_packT_w<<<dim3((WS + 255) / 256), 256, 0, stream>>>(Wtmp, WqkvT[l] + (size_t)1024 * 2048, 1024, 1024, (long)WS);
        pst_bias_comb<<<dim3(4), 256, 0, stream>>>(enc_Wk_b + l * PDBIG, enc_ink_W + l * WS,
                                                   enc_ink_b + l * PDBIG, bqkv[l] + 1024);
        pst_packT_w<<<dim3((WS + 255) / 256), 256, 0, stream>>>(enc_Wv_W + l * WS, WqkvT[l] + (size_t)2048 * 2048, 1024, 1024, (long)WS);
        pst_copy1024<<<dim3(4), 256, 0, stream>>>(enc_Wv_b + l * PDBIG, bqkv[l] + 2048);
        pst_packT_w<<<dim3((WE + 255) / 256), 256, 0, stream>>>(enc_emb_W + l * WE, WembT[l], 256, 1024, (long)WE);
        pst_packT_w<<<dim3((WE + 255) / 256), 256, 0, stream>>>(enc_out_W + l * WE, WoutT[l], 1024, 256, (long)WE);
    }

    // ----- embedding -----
    pst_embed4<<<dim3(PB * PN / 4), 256, 0, stream>>>(
        features, atomP, S0v, S1v, Cv, ln_g, ln_b, x, x_init);

    // ----- encoder layers, chunked -----
    for (int cb0 = 0; cb0 < PB; cb0 += CB) {
        float* xs = x + (size_t)cb0 * PN * PDD;
        const int Mi = (int)M;
        pst_pack_rows<<<dim3(Mi), 256, 0, stream>>>(xs, xp, 8);
        for (int l = 0; l < PL; ++l) {
            launch_gbf<1>(xp, WembT[l], enc_emb_b + (size_t)l * PDBIG, e, epack,
                          nullptr, nullptr, Mi, PDBIG, PDD, 0, 0, 0, 1, stream);
            launch_gbf<3>(epack, WqkvT[l], bqkv[l], q, nullptr, kT, vpT,
                          Mi, 3072, PDBIG, 0, 0, 0, 1, stream);
            pst_mask_kernel<<<dim3(Mi), 256, 0, stream>>>(e, maskb);
            pst_attnA<<<dim3(CB * 64), 256, 0, stream>>>(q, kT, maskb, features, Apack, cb0);
            launch_gbf<0>(Apack, vpT, nullptr, q, nullptr, nullptr, nullptr,
                          PN, PDBIG, PN, (long)PN * 1024, (long)PDBIG * 1024, (long)PN * PDBIG,
                          CB, stream);
            pst_spln<<<dim3(Mi), 256, 0, stream>>>(
                q, e, epack, enc_ln_g + (size_t)l * PDBIG, enc_ln_b + (size_t)l * PDBIG);
            launch_gbf<1>(epack, WoutT[l], enc_out_b + (size_t)l * PDD, xs, xp,
                          nullptr, nullptr, Mi, PDD, PDBIG, 0, 0, 0, 1, stream);
        }
    }

    // ----- pool -----
    pst_pool1<<<dim3(8, PB), 256, 0, stream>>>(features, x, x_init, partial);
    pst_pool2<<<dim3(PB), 256, 0, stream>>>(partial, ln_g, ln_b, out_W, out_b, (float*)d_out);
}

// Round 5
// 8937.692 us; speedup vs baseline: 3.4362x; 1.1697x over previous
//
#include <hip/hip_runtime.h>
#include <hip/hip_bf16.h>

// ---------------- problem constants ----------------
#define PB 64      // batch
#define PN 512     // set size
#define PFEA 102
#define PE 10
#define PDD 256    // d
#define PH 4
#define PDBIG 1024 // D = d*H
#define PL 3
#define PNDIST 100

typedef __attribute__((ext_vector_type(8))) short s8b;   // 8 bf16 (4 VGPRs)
typedef __attribute__((ext_vector_type(4))) float f4;    // 4 fp32 acc

typedef __attribute__((address_space(1))) const void gvoid_t;
typedef __attribute__((address_space(3))) void lvoid_t;
#define GLDS16(g, s) __builtin_amdgcn_global_load_lds((gvoid_t*)(g), (lvoid_t*)(s), 16, 0, 0)

__device__ __forceinline__ void split_bf16(float v, __hip_bfloat16& hi, __hip_bfloat16& lo) {
    hi = __float2bfloat16(v);
    lo = __float2bfloat16(v - __bfloat162float(hi));
}

// ---------------- reduction helpers (shfl-based, wave64) ----------------
__device__ __forceinline__ float block_sum1(float v, float* red, int tid) {
    #pragma unroll
    for (int off = 32; off >= 1; off >>= 1) v += __shfl_xor(v, off);
    __syncthreads();
    if ((tid & 63) == 0) red[tid >> 6] = v;
    __syncthreads();
    return red[0] + red[1] + red[2] + red[3];
}

template<int NR, bool MAXOP>
__device__ __forceinline__ void block_redN(float* v, float* red, int tid) {
    #pragma unroll
    for (int off = 32; off >= 1; off >>= 1) {
        #pragma unroll
        for (int r = 0; r < NR; ++r) {
            float o = __shfl_xor(v[r], off);
            v[r] = MAXOP ? fmaxf(v[r], o) : (v[r] + o);
        }
    }
    __syncthreads();
    if ((tid & 63) == 0) {
        #pragma unroll
        for (int r = 0; r < NR; ++r) red[(tid >> 6) * NR + r] = v[r];
    }
    __syncthreads();
    #pragma unroll
    for (int r = 0; r < NR; ++r) {
        float a = red[r], b = red[NR + r], c = red[2 * NR + r], d = red[3 * NR + r];
        v[r] = MAXOP ? fmaxf(fmaxf(a, b), fmaxf(c, d)) : ((a + b) + (c + d));
    }
    __syncthreads();
}

// ---------------- precompute kernels ----------------
__global__ __launch_bounds__(256) void pst_atomproj(
    const float* __restrict__ atom_fea, const float* __restrict__ comp_W,
    float* __restrict__ atomP)
{
    int a = blockIdx.x, tid = threadIdx.x;
    __shared__ float af[92];
    if (tid < 92) af[tid] = atom_fea[a * 92 + tid];
    __syncthreads();
    float s = 0.0f;
    #pragma unroll 4
    for (int k = 0; k < 92; ++k) s = fmaf(af[k], comp_W[k * PDD + tid], s);
    atomP[a * PDD + tid] = s;
}

__global__ __launch_bounds__(256) void pst_embW_reduce(
    const float* __restrict__ emb_W, float* __restrict__ S0, float* __restrict__ S1)
{
    int f = blockIdx.x, tid = threadIdx.x;
    float s0 = 0.0f, s1 = 0.0f;
    #pragma unroll
    for (int t = 0; t < PE; ++t) {
        float w = emb_W[(f * PE + t) * PDD + tid];
        float tf = (float)t / (float)PE;
        s0 += w;
        s1 = fmaf(2.0f * tf, w, s1);
    }
    S0[f * PDD + tid] = s0;
    S1[f * PDD + tid] = s1;
}

__global__ __launch_bounds__(256) void pst_embW_const(
    const float* __restrict__ emb_W, const float* __restrict__ comp_b,
    const float* __restrict__ emb_b, float* __restrict__ Cv)
{
    int tid = threadIdx.x;
    float s = comp_b[tid] + emb_b[tid];
    for (int m = 0; m < PNDIST * PE; ++m) {
        float tf = (float)(m % PE) / (float)PE;
        s = fmaf(tf * tf, emb_W[m * PDD + tid], s);
    }
    Cv[tid] = s;
}

// ---------------- embed: 4 rows/block ----------------
__global__ __launch_bounds__(256) void pst_embed4(
    const float* __restrict__ features, const float* __restrict__ atomP,
    const float* __restrict__ S0, const float* __restrict__ S1,
    const float* __restrict__ Cv, const float* __restrict__ ln_g,
    const float* __restrict__ ln_b, float* __restrict__ x, float* __restrict__ x_init)
{
    int r0 = blockIdx.x * 4, tid = threadIdx.x;
    __shared__ float uv[4][PNDIST];
    __shared__ int idxs[4];
    __shared__ float red[16];
    for (int m = tid; m < 4 * PNDIST; m += 256) {
        int r = m / PNDIST, f = m - r * PNDIST;
        uv[r][f] = 1.0f - features[(long)(r0 + r) * PFEA + 1 + f];
    }
    if (tid < 4) idxs[tid] = (int)features[(long)(r0 + tid) * PFEA + PFEA - 1];
    __syncthreads();

    float acc[4];
    float cv = Cv[tid];
    #pragma unroll
    for (int r = 0; r < 4; ++r) acc[r] = cv + atomP[idxs[r] * PDD + tid];
    for (int f = 0; f < PNDIST; ++f) {
        float s0 = S0[f * PDD + tid], s1 = S1[f * PDD + tid];
        #pragma unroll
        for (int r = 0; r < 4; ++r) {
            float u = uv[r][f];
            acc[r] = fmaf(u, fmaf(u, s0, s1), acc[r]);
        }
    }
    float mean[4];
    #pragma unroll
    for (int r = 0; r < 4; ++r) mean[r] = acc[r];
    block_redN<4, false>(mean, red, tid);
    float var[4], dv[4];
    #pragma unroll
    for (int r = 0; r < 4; ++r) { mean[r] *= (1.0f / PDD); dv[r] = acc[r] - mean[r]; var[r] = dv[r] * dv[r]; }
    block_redN<4, false>(var, red, tid);
    #pragma unroll
    for (int r = 0; r < 4; ++r) {
        float y = dv[r] * rsqrtf(var[r] * (1.0f / PDD) + 1e-5f) * ln_g[tid] + ln_b[tid];
        long o = (long)(r0 + r) * PDD + tid;
        x[o] = y;
        x_init[o] = y;
    }
}

// ---------------- bf16 split-K MFMA GEMM ----------------
// A pack: M x 2K [hi|lo] row-major; B pack: N x 2K [hi|lo] (= B^T) row-major.
// computes Ah@Bh + Al@Bh + Ah@Bl via K-loop over 3K with block remap.
// MODE 0: C f32 (ldc=Nw), batched via z.
// MODE 1: C f32 + P row-pack (M x 2*Nw).
// MODE 3: qkv routing (Nw=3072): n<1024 -> Pq per-head pack [bb*4+h][512][hi256|lo256];
//         n<2048 -> Pk same; else -> Pv transposed pack [bb][vcol][hi512|lo512].
// MODE 4: P row-pack only (no C).
template<int MODE>
__global__ __launch_bounds__(256) void pst_gemm_bf16(
    const __hip_bfloat16* __restrict__ Ap, const __hip_bfloat16* __restrict__ Bp,
    const float* __restrict__ bias, float* __restrict__ C,
    __hip_bfloat16* __restrict__ P, __hip_bfloat16* __restrict__ Pq,
    __hip_bfloat16* __restrict__ Pk, __hip_bfloat16* __restrict__ Pv,
    int K, int Nw, long strideA, long strideB, long strideC)
{
    const int lda = 2 * K, ldb = 2 * K;
    int bz = blockIdx.z;
    Ap += (long)bz * strideA; Bp += (long)bz * strideB;
    if (MODE == 0) C += (long)bz * strideC;

    // T1: bijective XCD-aware swizzle over the 2D tile grid (all launches have nwg%8==0)
    int gx = gridDim.x;
    int lin = blockIdx.y * gx + blockIdx.x;
    int nwg = gx * gridDim.y;
    if ((nwg & 7) == 0) { int cpx = nwg >> 3; lin = (lin & 7) * cpx + (lin >> 3); }
    int m0 = (lin / gx) * 128, n0 = (lin % gx) * 128;

    __shared__ __hip_bfloat16 As[128 * 32];
    __shared__ __hip_bfloat16 Bs[128 * 32];

    int tid = threadIdx.x;
    int w = tid >> 6, l = tid & 63;
    int r4 = tid >> 2;
    int c8 = (tid & 3) * 8;
    int lr = l & 15, kb = l >> 4;
    int wm = (w >> 1) * 64, wn = (w & 1) * 64;

    f4 acc[4][4] = {};

    const int K3 = 3 * K;
    for (int k0 = 0; k0 < K3; k0 += 32) {
        int kA = (k0 < 2 * K) ? k0 : k0 - 2 * K;   // hi, lo, hi
        int kB = (k0 < K) ? k0 : k0 - K;           // hi, hi, lo
        const __hip_bfloat16* ga = Ap + (long)(m0 + r4) * lda + kA + c8;
        const __hip_bfloat16* gb = Bp + (long)(n0 + r4) * ldb + kB + c8;
        GLDS16(ga,             As + w * 512);
        GLDS16(ga + 64L * lda, As + 2048 + w * 512);
        GLDS16(gb,             Bs + w * 512);
        GLDS16(gb + 64L * ldb, Bs + 2048 + w * 512);
        __syncthreads();

        s8b af[4], bf[4];
        #pragma unroll
        for (int f = 0; f < 4; ++f) {
            af[f] = *(const s8b*)(As + (wm + f * 16 + lr) * 32 + kb * 8);
            bf[f] = *(const s8b*)(Bs + (wn + f * 16 + lr) * 32 + kb * 8);
        }
        #pragma unroll
        for (int i = 0; i < 4; ++i)
            #pragma unroll
            for (int j = 0; j < 4; ++j)
                acc[i][j] = __builtin_amdgcn_mfma_f32_16x16x32_bf16(af[i], bf[j], acc[i][j], 0, 0, 0);
        __syncthreads();
    }

    // C/D layout: col=lane&15, row=(lane>>4)*4+reg [verified m89/m91]
    #pragma unroll
    for (int i = 0; i < 4; ++i) {
        #pragma unroll
        for (int j = 0; j < 4; ++j) {
            #pragma unroll
            for (int r = 0; r < 4; ++r) {
                int m = m0 + wm + i * 16 + kb * 4 + r;
                int n = n0 + wn + j * 16 + lr;
                float val = acc[i][j][r] + (bias ? bias[n] : 0.0f);
                if (MODE == 0) {
                    C[(long)m * Nw + n] = val;
                } else if (MODE == 1) {
                    C[(long)m * Nw + n] = val;
                    __hip_bfloat16 hi, lo; split_bf16(val, hi, lo);
                    long b = (long)m * (2 * Nw) + n;
                    P[b] = hi; P[b + Nw] = lo;
                } else if (MODE == 4) {
                    __hip_bfloat16 hi, lo; split_bf16(val, hi, lo);
                    long b = (long)m * (2 * Nw) + n;
                    P[b] = hi; P[b + Nw] = lo;
                } else { // MODE 3: qkv routing
                    int bb = m >> 9, rr = m & 511;
                    int region = n >> 10, np = n & 1023;
                    __hip_bfloat16 hi, lo; split_bf16(val, hi, lo);
                    if (region < 2) {
                        __hip_bfloat16* dst = (region == 0) ? Pq : Pk;
                        int h = np >> 8, kk = np & 255;
                        long b = (((long)bb * 4 + h) * 512 + rr) * 512 + kk;
                        dst[b] = hi; dst[b + 256] = lo;
                    } else {
                        long base = ((long)bb * PDBIG + np) * 1024;
                        Pv[base + rr] = hi; Pv[base + 512 + rr] = lo;
                    }
                }
            }
        }
    }
}

// ---------------- pack helpers ----------------
__global__ __launch_bounds__(256) void pst_pack_rows(
    const float* __restrict__ src, __hip_bfloat16* __restrict__ dst, int kshift)
{
    long i = (long)blockIdx.x * 256 + threadIdx.x;
    int K = 1 << kshift;
    long m = i >> kshift; int k = (int)(i & (K - 1));
    float v = src[i];
    __hip_bfloat16 hi, lo; split_bf16(v, hi, lo);
    long b = (m << (kshift + 1)) + k;
    dst[b] = hi; dst[b + K] = lo;
}

__global__ __launch_bounds__(256) void pst_packT_w(
    const float* __restrict__ W, __hip_bfloat16* __restrict__ dst, int K, int N, long total)
{
    long i = (long)blockIdx.x * 256 + threadIdx.x;
    if (i >= total) return;
    int k = (int)(i / N), n = (int)(i - (long)k * N);
    float v = W[i];
    __hip_bfloat16 hi, lo; split_bf16(v, hi, lo);
    long b = (long)n * (2 * K) + k;
    dst[b] = hi; dst[b + K] = lo;
}

__global__ __launch_bounds__(256) void pst_bias_comb(
    const float* __restrict__ b1, const float* __restrict__ W2,
    const float* __restrict__ b2, float* __restrict__ out)
{
    int n = blockIdx.x * 256 + threadIdx.x;
    float s = b2[n];
    for (int k2 = 0; k2 < PDBIG; ++k2)
        s = fmaf(b1[k2], W2[(long)k2 * PDBIG + n], s);
    out[n] = s;
}

__global__ __launch_bounds__(256) void pst_copy1024(
    const float* __restrict__ src, float* __restrict__ dst)
{
    int i = blockIdx.x * 256 + threadIdx.x;
    dst[i] = src[i];
}

// ---------------- mask: sum|e| == 0 (from epack hi/lo) ----------------
__global__ __launch_bounds__(256) void pst_mask_kernel(
    const __hip_bfloat16* __restrict__ ep, float* __restrict__ mask)
{
    int r = blockIdx.x, tid = threadIdx.x;
    __shared__ float red[4];
    float s = 0.0f;
    #pragma unroll
    for (int j = 0; j < 4; ++j) {
        int i = tid + j * 256;
        s += fabsf(__bfloat162float(ep[(long)r * 2048 + i]))
           + fabsf(__bfloat162float(ep[(long)r * 2048 + 1024 + i]));
    }
    float tot = block_sum1(s, red, tid);
    if (tid == 0) mask[r] = (tot == 0.0f) ? 1.0f : 0.0f;
}

// ---------------- attention softmax: S -> mask -> softmax -> mean h -> *w -> renorm -> Apack ----
// S layout: [bLoc*4+h][512 qrow][512 kcol] f32 (raw scores, scale applied here)
__global__ __launch_bounds__(256) void pst_attnSM(
    const float* __restrict__ S, const float* __restrict__ maskb,
    const float* __restrict__ features, __hip_bfloat16* __restrict__ Apack,
    int bGlobBase)
{
    int blk = blockIdx.x;
    int bLoc = blk >> 6;
    int q0 = (blk & 63) << 3;
    int tid = threadIdx.x;
    __shared__ float wm[PN];
    __shared__ float red[32];

    int bGlob = bGlobBase + bLoc;
    for (int c = tid; c < PN; c += 256) wm[c] = features[((long)bGlob * PN + c) * PFEA];
    bool bad0 = maskb[bLoc * PN + tid] != 0.0f;
    bool bad1 = maskb[bLoc * PN + tid + 256] != 0.0f;
    __syncthreads();

    const float scale = 0.0625f;   // 1/sqrt(256)
    float pacc[8][2] = {};

    for (int h = 0; h < PH; ++h) {
        const float* Sh = S + (((long)(bLoc * 4 + h)) * 512 + q0) * 512;
        float s[8][2], mrow[8];
        #pragma unroll
        for (int r = 0; r < 8; ++r) {
            float a = Sh[(long)r * 512 + tid];
            float b = Sh[(long)r * 512 + tid + 256];
            a = bad0 ? -1e9f : a * scale;
            b = bad1 ? -1e9f : b * scale;
            s[r][0] = a; s[r][1] = b;
            mrow[r] = fmaxf(a, b);
        }
        block_redN<8, true>(mrow, red, tid);
        float srow[8];
        #pragma unroll
        for (int r = 0; r < 8; ++r) {
            float e0 = __expf(s[r][0] - mrow[r]);
            float e1 = __expf(s[r][1] - mrow[r]);
            s[r][0] = e0; s[r][1] = e1;
            srow[r] = e0 + e1;
        }
        block_redN<8, false>(srow, red, tid);
        #pragma unroll
        for (int r = 0; r < 8; ++r) {
            float inv = 1.0f / srow[r];
            pacc[r][0] += s[r][0] * inv;
            pacc[r][1] += s[r][1] * inv;
        }
    }

    float arow[8];
    #pragma unroll
    for (int r = 0; r < 8; ++r) {
        pacc[r][0] *= wm[tid];
        pacc[r][1] *= wm[tid + 256];
        arow[r] = pacc[r][0] + pacc[r][1];
    }
    block_redN<8, false>(arow, red, tid);
    #pragma unroll
    for (int r = 0; r < 8; ++r) {
        float inv = 1.0f / arow[r];
        long rowb = ((long)bLoc * PN + q0 + r) * 1024;
        __hip_bfloat16 hi, lo;
        split_bf16(pacc[r][0] * inv, hi, lo);
        Apack[rowb + tid] = hi; Apack[rowb + 512 + tid] = lo;
        split_bf16(pacc[r][1] * inv, hi, lo);
        Apack[rowb + tid + 256] = hi; Apack[rowb + 512 + tid + 256] = lo;
    }
}

// ---------------- xe = LN(e + softplus(att)) over epack (in place) ----------------
__global__ __launch_bounds__(256) void pst_spln(
    const float* __restrict__ att, __hip_bfloat16* __restrict__ ep,
    const float* __restrict__ g, const float* __restrict__ bb)
{
    int r = blockIdx.x, tid = threadIdx.x;
    __shared__ float red[4];
    float v[4];
    float s = 0.0f;
    #pragma unroll
    for (int j = 0; j < 4; ++j) {
        int i = tid + j * 256;
        float a = att[(long)r * PDBIG + i];
        float sp = (a > 20.0f) ? a : log1pf(expf(a));
        float ev = __bfloat162float(ep[(long)r * 2048 + i])
                 + __bfloat162float(ep[(long)r * 2048 + 1024 + i]);
        v[j] = ev + sp;
        s += v[j];
    }
    float mean = block_sum1(s, red, tid) * (1.0f / PDBIG);
    float vs = 0.0f;
    #pragma unroll
    for (int j = 0; j < 4; ++j) { float dv = v[j] - mean; vs += dv * dv; }
    float var = block_sum1(vs, red, tid) * (1.0f / PDBIG);
    float inv = rsqrtf(var + 1e-5f);
    #pragma unroll
    for (int j = 0; j < 4; ++j) {
        int i = tid + j * 256;
        float y = (v[j] - mean) * inv * g[i] + bb[i];
        __hip_bfloat16 hi, lo; split_bf16(y, hi, lo);
        ep[(long)r * 2048 + i] = hi;
        ep[(long)r * 2048 + 1024 + i] = lo;
    }
}

// ---------------- pool (2-phase) ----------------
__global__ __launch_bounds__(256) void pst_pool1(
    const float* __restrict__ features, const float* __restrict__ x,
    const float* __restrict__ xi, float* __restrict__ partial)
{
    int p = blockIdx.x, b = blockIdx.y, tid = threadIdx.x;
    float acc = 0.0f;
    for (int n = p * 64; n < p * 64 + 64; ++n) {
        float w = features[((long)b * PN + n) * PFEA];
        long off = ((long)b * PN + n) * PDD + tid;
        acc = fmaf(w, x[off] + xi[off], acc);
    }
    partial[((long)b * 8 + p) * PDD + tid] = acc;
}

__global__ __launch_bounds__(256) void pst_pool2(
    const float* __restrict__ partial, const float* __restrict__ ln_g,
    const float* __restrict__ ln_b, const float* __restrict__ out_W,
    const float* __restrict__ out_b, float* __restrict__ out)
{
    int b = blockIdx.x, tid = threadIdx.x;
    __shared__ float red[4];
    float acc = 0.0f;
    #pragma unroll
    for (int p = 0; p < 8; ++p) acc += partial[((long)b * 8 + p) * PDD + tid];
    float mean = block_sum1(acc, red, tid) * (1.0f / PDD);
    float dv = acc - mean;
    float var = block_sum1(dv * dv, red, tid) * (1.0f / PDD);
    float y = dv * rsqrtf(var + 1e-5f) * ln_g[tid] + ln_b[tid];
    float s = block_sum1(y * out_W[tid], red, tid);
    if (tid == 0) out[b] = s + out_b[0];
}

// ---------------- host ----------------
template<int MODE>
static void launch_gbf(const __hip_bfloat16* A, const __hip_bfloat16* B, const float* bias,
                       float* C, __hip_bfloat16* P, __hip_bfloat16* Pq,
                       __hip_bfloat16* Pk, __hip_bfloat16* Pv,
                       int M, int Nw, int K, long sA, long sB, long sC, int batch,
                       hipStream_t st)
{
    dim3 grid(Nw / 128, M / 128, batch);
    pst_gemm_bf16<MODE><<<grid, dim3(256), 0, st>>>(A, B, bias, C, P, Pq, Pk, Pv, K, Nw, sA, sB, sC);
}

extern "C" void kernel_launch(void* const* d_in, const int* in_sizes, int n_in,
                              void* d_out, int out_size, void* d_ws, size_t ws_size,
                              hipStream_t stream)
{
    const float* features  = (const float*)d_in[0];
    const float* atom_fea  = (const float*)d_in[1];
    const float* comp_W    = (const float*)d_in[2];
    const float* comp_b    = (const float*)d_in[3];
    const float* emb_W     = (const float*)d_in[4];
    const float* emb_b     = (const float*)d_in[5];
    const float* ln_g      = (const float*)d_in[6];
    const float* ln_b      = (const float*)d_in[7];
    const float* enc_emb_W = (const float*)d_in[8];
    const float* enc_emb_b = (const float*)d_in[9];
    const float* enc_Wq_W  = (const float*)d_in[10];
    const float* enc_Wq_b  = (const float*)d_in[11];
    const float* enc_Wk_W  = (const float*)d_in[12];
    const float* enc_Wk_b  = (const float*)d_in[13];
    const float* enc_Wv_W  = (const float*)d_in[14];
    const float* enc_Wv_b  = (const float*)d_in[15];
    const float* enc_inq_W = (const float*)d_in[16];
    const float* enc_inq_b = (const float*)d_in[17];
    const float* enc_ink_W = (const float*)d_in[18];
    const float* enc_ink_b = (const float*)d_in[19];
    const float* enc_ln_g  = (const float*)d_in[20];
    const float* enc_ln_b  = (const float*)d_in[21];
    const float* enc_out_W = (const float*)d_in[22];
    const float* enc_out_b = (const float*)d_in[23];
    const float* out_W     = (const float*)d_in[24];
    const float* out_b     = (const float*)d_in[25];

    // ----- workspace layout (floats) -----
    const size_t SZ_X = (size_t)PB * PN * PDD;
    float* ws = (float*)d_ws;
    size_t off = 0;
    float* x      = ws + off; off += SZ_X;
    float* x_init = ws + off; off += SZ_X;
    __hip_bfloat16* WembT[PL]; __hip_bfloat16* WqkvT[PL]; __hip_bfloat16* WoutT[PL];
    float* bqkv[PL];
    for (int l = 0; l < PL; ++l) {
        WembT[l] = (__hip_bfloat16*)(ws + off); off += (size_t)1024 * 512 / 2;
        WqkvT[l] = (__hip_bfloat16*)(ws + off); off += (size_t)3072 * 2048 / 2;
        WoutT[l] = (__hip_bfloat16*)(ws + off); off += (size_t)256 * 2048 / 2;
        bqkv[l]  = ws + off; off += 3072;
    }
    float* Wtmp = ws + off; off += (size_t)1024 * 1024;
    __hip_bfloat16* pA = (__hip_bfloat16*)(ws + off); off += (size_t)1024 * 2048 / 2;
    __hip_bfloat16* pB = (__hip_bfloat16*)(ws + off); off += (size_t)1024 * 2048 / 2;
    float* atomP = ws + off; off += (size_t)100 * PDD;
    float* S0v   = ws + off; off += (size_t)PNDIST * PDD;
    float* S1v   = ws + off; off += (size_t)PNDIST * PDD;
    float* Cv    = ws + off; off += PDD;
    float* partial = ws + off; off += (size_t)PB * 8 * PDD;
    size_t persistf = off;

    // per-row (fl): xp 256 + epack 1024 + qp 1024 + kp 1024 + vpT 1024 + S 2048 + Apack 512 + mask 1
    int CB = 64;
    while (CB > 1) {
        size_t M = (size_t)CB * PN;
        size_t chunk = M * (256 + 1024 + 1024 + 1024 + 1024 + 2048 + 512 + 1);
        if ((persistf + chunk) * sizeof(float) <= ws_size) break;
        CB >>= 1;
    }
    const size_t M = (size_t)CB * PN;

    __hip_bfloat16* xp    = (__hip_bfloat16*)(ws + off); off += M * 256;
    __hip_bfloat16* epack = (__hip_bfloat16*)(ws + off); off += M * 1024;
    __hip_bfloat16* qp    = (__hip_bfloat16*)(ws + off); off += M * 1024;
    __hip_bfloat16* kp    = (__hip_bfloat16*)(ws + off); off += M * 1024;
    __hip_bfloat16* vpT   = (__hip_bfloat16*)(ws + off); off += M * 1024;
    float* Sbuf           = ws + off;                    off += M * 2048;  // scores, then att
    __hip_bfloat16* Apack = (__hip_bfloat16*)(ws + off); off += M * 512;
    float* maskb          = ws + off;                    off += M;

    // ----- precompute: embed reductions -----
    pst_atomproj<<<dim3(100), 256, 0, stream>>>(atom_fea, comp_W, atomP);
    pst_embW_reduce<<<dim3(PNDIST), 256, 0, stream>>>(emb_W, S0v, S1v);
    pst_embW_const<<<dim3(1), 256, 0, stream>>>(emb_W, comp_b, emb_b, Cv);

    // ----- precompute: weight packs / combined q,k -----
    const size_t WS = (size_t)PDBIG * PDBIG;
    const size_t WE = (size_t)PDD * PDBIG;
    for (int l = 0; l < PL; ++l) {
        pst_pack_rows<<<dim3(WS / 256), 256, 0, stream>>>(enc_Wq_W + l * WS, pA, 10);
        pst_packT_w<<<dim3((WS + 255) / 256), 256, 0, stream>>>(enc_inq_W + l * WS, pB, 1024, 1024, (long)WS);
        launch_gbf<0>(pA, pB, nullptr, Wtmp, nullptr, nullptr, nullptr, nullptr,
                      1024, 1024, 1024, 0, 0, 0, 1, stream);
        pst_packT_w<<<dim3((WS + 255) / 256), 256, 0, stream>>>(Wtmp, WqkvT[l], 1024, 1024, (long)WS);
        pst_bias_comb<<<dim3(4), 256, 0, stream>>>(enc_Wq_b + l * PDBIG, enc_inq_W + l * WS,
                                                   enc_inq_b + l * PDBIG, bqkv[l]);
        pst_pack_rows<<<dim3(WS / 256), 256, 0, stream>>>(enc_Wk_W + l * WS, pA, 10);
        pst_packT_w<<<dim3((WS + 255) / 256), 256, 0, stream>>>(enc_ink_W + l * WS, pB, 1024, 1024, (long)WS);
        launch_gbf<0>(pA, pB, nullptr, Wtmp, nullptr, nullptr, nullptr, nullptr,
                      1024, 1024, 1024, 0, 0, 0, 1, stream);
        pst_packT_w<<<dim3((WS + 255) / 256), 256, 0, stream>>>(Wtmp, WqkvT[l] + (size_t)1024 * 2048, 1024, 1024, (long)WS);
        pst_bias_comb<<<dim3(4), 256, 0, stream>>>(enc_Wk_b + l * PDBIG, enc_ink_W + l * WS,
                                                   enc_ink_b + l * PDBIG, bqkv[l] + 1024);
        pst_packT_w<<<dim3((WS + 255) / 256), 256, 0, stream>>>(enc_Wv_W + l * WS, WqkvT[l] + (size_t)2048 * 2048, 1024, 1024, (long)WS);
        pst_copy1024<<<dim3(4), 256, 0, stream>>>(enc_Wv_b + l * PDBIG, bqkv[l] + 2048);
        pst_packT_w<<<dim3((WE + 255) / 256), 256, 0, stream>>>(enc_emb_W + l * WE, WembT[l], 256, 1024, (long)WE);
        pst_packT_w<<<dim3((WE + 255) / 256), 256, 0, stream>>>(enc_out_W + l * WE, WoutT[l], 1024, 256, (long)WE);
    }

    // ----- embedding -----
    pst_embed4<<<dim3(PB * PN / 4), 256, 0, stream>>>(
        features, atomP, S0v, S1v, Cv, ln_g, ln_b, x, x_init);

    // ----- encoder layers, chunked -----
    for (int cb0 = 0; cb0 < PB; cb0 += CB) {
        float* xs = x + (size_t)cb0 * PN * PDD;
        const int Mi = (int)M;
        pst_pack_rows<<<dim3(Mi), 256, 0, stream>>>(xs, xp, 8);
        for (int l = 0; l < PL; ++l) {
            // epack = pack(xp @ WembT + b)  (MODE 4: pack only)
            launch_gbf<4>(xp, WembT[l], enc_emb_b + (size_t)l * PDBIG, nullptr, epack,
                          nullptr, nullptr, nullptr, Mi, PDBIG, PDD, 0, 0, 0, 1, stream);
            // fused qkv -> qp, kp (per-head packs), vpT
            launch_gbf<3>(epack, WqkvT[l], bqkv[l], nullptr, nullptr, qp, kp, vpT,
                          Mi, 3072, PDBIG, 0, 0, 0, 1, stream);
            // mask from epack
            pst_mask_kernel<<<dim3(Mi), 256, 0, stream>>>(epack, maskb);
            // S = q @ k^T per (batch, head): 512x512x256 split-GEMM, batched CB*4
            launch_gbf<0>(qp, kp, nullptr, Sbuf, nullptr, nullptr, nullptr, nullptr,
                          512, 512, 256, (long)512 * 512, (long)512 * 512, (long)512 * 512,
                          CB * 4, stream);
            // softmax/mean/renorm -> Apack
            pst_attnSM<<<dim3(CB * 64), 256, 0, stream>>>(Sbuf, maskb, features, Apack, cb0);
            // att = A @ v (batched) -> reuse Sbuf (f32, M x 1024)
            launch_gbf<0>(Apack, vpT, nullptr, Sbuf, nullptr, nullptr, nullptr, nullptr,
                          PN, PDBIG, PN, (long)PN * 1024, (long)PDBIG * 1024, (long)PN * PDBIG,
                          CB, stream);
            // xe = LN(e + softplus(att)) in place over epack
            pst_spln<<<dim3(Mi), 256, 0, stream>>>(
                Sbuf, epack, enc_ln_g + (size_t)l * PDBIG, enc_ln_b + (size_t)l * PDBIG);
            // x = xe @ WoutT + b  (f32 + next-layer xp pack)
            launch_gbf<1>(epack, WoutT[l], enc_out_b + (size_t)l * PDD, xs, xp,
                          nullptr, nullptr, nullptr, Mi, PDD, PDBIG, 0, 0, 0, 1, stream);
        }
    }

    // ----- pool -----
    pst_pool1<<<dim3(8, PB), 256, 0, stream>>>(features, x, x_init, partial);
    pst_pool2<<<dim3(PB), 256, 0, stream>>>(partial, ln_g, ln_b, out_W, out_b, (float*)d_out);
}